// Round 10
// baseline (589.112 us; speedup 1.0000x reference)
//
#include <hip/hip_runtime.h>
#include <hip/hip_bf16.h>

// ---------------------------------------------------------------------------
// HetergatWOConcatFeat — round 11:
//  - GEMM tile BN 64 -> 128 (grid.y 8 -> 4): halves the A-panel re-read that
//    round-10 counters exposed (FETCH 169MB for ~21MB of inputs, MfmaUtil
//    8.7%). acc[2][8], 32 MFMA/K-step, LDS 32KB. Fused-st epilogue covers
//    2 heads per block. A f32 staging vectorized to 2x float4.
//  - Algebraic fusion (hp = hemb @ Wg), favec2, aggregate, final, CSR,
//    grid.z type-batching unchanged from round 10.
// ---------------------------------------------------------------------------

typedef __hip_bfloat16 bf16;
typedef __attribute__((ext_vector_type(8))) short short8;
typedef __attribute__((ext_vector_type(4))) float f32x4;

__device__ __forceinline__ float bf2f(bf16 v) { return __bfloat162float(v); }
__device__ __forceinline__ float ldin(const void* p, long i, int f32) {
  return f32 ? ((const float*)p)[i] : bf2f(((const bf16*)p)[i]);
}
__device__ __forceinline__ short f2bfbits(float f) {
  bf16 h = __float2bfloat16(f);
  return *reinterpret_cast<short*>(&h);
}
__device__ __forceinline__ float bfbits2f(short b) {
  unsigned u = ((unsigned)(unsigned short)b) << 16;
  return __uint_as_float(u);
}

struct GArg {
  const void* A[2];
  const void* B[2];
  bf16* C[2];
  const void* sa[2];
  const void* sb[2];
  float* sv[2];
  float* tv[2];
};

struct AArg {
  const bf16* hp[2];
  const float* sv[2];
  const float* tv[2];
  const int* rp[2];
  const int* col[2];
  void* out[2];
};

// Detect input dtype: read first 2048 elements of hemb0 as bf16. If the data
// is really f32, the mantissa halves decode to huge/NaN values.
__global__ __launch_bounds__(64) void detect_kernel(const void* __restrict__ x,
                                                    int* __restrict__ flag) {
  int tid = threadIdx.x;
  float m = 0.f;
  for (int i = tid; i < 2048; i += 64) {
    float v = fabsf(bf2f(((const bf16*)x)[i]));
    if (!(v <= 1e3f)) v = 1e9f;  // NaN/Inf/big -> force detect
    m = fmaxf(m, v);
  }
#pragma unroll
  for (int off = 32; off; off >>= 1) m = fmaxf(m, __shfl_xor(m, off));
  if (tid == 0) flag[0] = (m > 1e3f) ? 1 : 0;
}

// ---------------------------------------------------------------------------
// MFMA GEMM: C[M][Nc] (bf16, row-major) = A[M][K] @ B[K][Nc], fp32 accum.
// amode: 0 = A ws bf16 row-major; 1 = A input tensor (dtype by flag).
// bmode: 0 = B row-major [K][Nc] input; 1 = B head-blocked [H][K][64] input;
//        2 = B row-major [K][Nc] WS bf16 (flag-independent).
// Tile: BM=128, BN=128, BK=64. 256 threads = 4 waves; wave owns 32 rows x
// all 128 cols (acc[2][8], 32 MFMA per K-step). LDS 32KB, XOR-swizzled.
// blockIdx.z selects the type-slot in GArg. Fused st when sv[z] != null
// (requires Nc=512: block covers heads 2*blockIdx.y and 2*blockIdx.y+1).
// ---------------------------------------------------------------------------
#define GBM 128
#define GBN 128
#define GBK 64

__device__ __forceinline__ int swz(int row, int kbyte) {
  return row * 128 + (kbyte ^ ((row & 7) << 4));
}

__global__ __launch_bounds__(256) void gemm_mfma(GArg g, int amode, int bmode,
                                                 int M, int K, int Nc,
                                                 const int* __restrict__ flag) {
  __shared__ bf16 As[GBM * GBK];
  __shared__ bf16 Bs[GBN * GBK];
  const int z = blockIdx.z;
  const void* __restrict__ A = g.A[z];
  const void* __restrict__ B = g.B[z];
  bf16* __restrict__ C = g.C[z];
  const void* stasrc = g.sa[z];
  const void* statrg = g.sb[z];
  float* svp = g.sv[z];
  float* tvp = g.tv[z];
  const int f32 = flag[0];
  const int af32 = (amode == 1) ? f32 : 0;
  const int bf32 = (bmode == 2) ? 0 : f32;
  const int m0 = blockIdx.x * GBM;
  const int n0 = blockIdx.y * GBN;
  const int tid = threadIdx.x;
  const int lane = tid & 63;
  const int wrow = (tid >> 6) * 32;

  f32x4 acc[2][8];
#pragma unroll
  for (int m = 0; m < 2; m++)
#pragma unroll
    for (int n = 0; n < 8; n++)
#pragma unroll
      for (int r = 0; r < 4; r++) acc[m][n][r] = 0.f;

  for (int kt = 0; kt < K; kt += GBK) {
    // ---- stage A: 128 rows x 64 k (bf16), 1024 16B slots, 4 per thread ----
#pragma unroll
    for (int j = 0; j < 4; j++) {
      int idx = tid + j * 256;       // 0..1023
      int row = idx >> 3;            // 0..127
      int ks = idx & 7;              // 16B slot within row
      int gm = m0 + row;
      short8 v;
#pragma unroll
      for (int e = 0; e < 8; e++) v[e] = 0;
      if (gm < M) {
        long base = (long)gm * K + kt + ks * 8;
        if (!af32) {
          v = *(const short8*)((const bf16*)A + base);
        } else {
          const float* Af = (const float*)A + base;
          float4 x0 = *(const float4*)Af;
          float4 x1 = *(const float4*)(Af + 4);
          v[0] = f2bfbits(x0.x); v[1] = f2bfbits(x0.y);
          v[2] = f2bfbits(x0.z); v[3] = f2bfbits(x0.w);
          v[4] = f2bfbits(x1.x); v[5] = f2bfbits(x1.y);
          v[6] = f2bfbits(x1.z); v[7] = f2bfbits(x1.w);
        }
      }
      *(short8*)((char*)As + swz(row, ks * 16)) = v;
    }
    // ---- stage B transposed: Bs[col][k], 128 cols x 64 k, 4 per thread ----
#pragma unroll
    for (int j = 0; j < 4; j++) {
      int idx = tid + j * 256;       // 0..1023
      int col = idx >> 3;            // 0..127
      int ks = idx & 7;
      int k = kt + ks * 8;
      int gcol = n0 + col;
      long base;
      int cstr;
      if (bmode == 1) { base = ((long)(gcol >> 6) * K + k) * 64 + (gcol & 63); cstr = 64; }
      else { base = (long)k * Nc + gcol; cstr = Nc; }
      short8 v;
      if (bf32) {
        const float* Bf = (const float*)B;
#pragma unroll
        for (int e = 0; e < 8; e++) v[e] = f2bfbits(Bf[base + (long)e * cstr]);
      } else {
        const bf16* Bh = (const bf16*)B;
#pragma unroll
        for (int e = 0; e < 8; e++) v[e] = *(const short*)&Bh[base + (long)e * cstr];
      }
      *(short8*)((char*)Bs + swz(col, ks * 16)) = v;
    }
    __syncthreads();
    // ---- compute: 2 k-halves of 32, per wave 2x8 fragments ----
#pragma unroll
    for (int kh = 0; kh < 2; kh++) {
      int klane = kh * 64 + ((lane >> 4) << 4);  // byte offset of k within row
      short8 af[2], bfr[8];
#pragma unroll
      for (int m = 0; m < 2; m++) {
        int row = wrow + m * 16 + (lane & 15);
        af[m] = *(const short8*)((const char*)As + swz(row, klane));
      }
#pragma unroll
      for (int n = 0; n < 8; n++) {
        int col = n * 16 + (lane & 15);
        bfr[n] = *(const short8*)((const char*)Bs + swz(col, klane));
      }
#pragma unroll
      for (int m = 0; m < 2; m++)
#pragma unroll
        for (int n = 0; n < 8; n++)
          acc[m][n] = __builtin_amdgcn_mfma_f32_16x16x32_bf16(af[m], bfr[n], acc[m][n], 0, 0, 0);
    }
    __syncthreads();
  }
  // ---- fused st: s/t from fp32 acc. Block covers heads 2y and 2y+1 ----
  if (svp) {
    const int cl = lane & 15;
    float av[8], bv[8];
#pragma unroll
    for (int n = 0; n < 8; n++) {
      av[n] = ldin(stasrc, blockIdx.y * 128 + n * 16 + cl, f32);
      bv[n] = ldin(statrg, blockIdx.y * 128 + n * 16 + cl, f32);
    }
#pragma unroll
    for (int m = 0; m < 2; m++) {
#pragma unroll
      for (int r = 0; r < 4; r++) {
        float s0 = 0.f, t0 = 0.f, s1 = 0.f, t1 = 0.f;
#pragma unroll
        for (int n = 0; n < 4; n++) {
          s0 += acc[m][n][r] * av[n];
          t0 += acc[m][n][r] * bv[n];
        }
#pragma unroll
        for (int n = 4; n < 8; n++) {
          s1 += acc[m][n][r] * av[n];
          t1 += acc[m][n][r] * bv[n];
        }
#pragma unroll
        for (int off = 1; off <= 8; off <<= 1) {
          s0 += __shfl_xor(s0, off);
          t0 += __shfl_xor(t0, off);
          s1 += __shfl_xor(s1, off);
          t1 += __shfl_xor(t1, off);
        }
        int row = m0 + wrow + m * 16 + ((lane >> 4) << 2) + r;
        if (cl == 0 && row < M) {
          int h0 = blockIdx.y * 2;
          svp[(long)row * 8 + h0] = s0;
          tvp[(long)row * 8 + h0] = t0;
          svp[(long)row * 8 + h0 + 1] = s1;
          tvp[(long)row * 8 + h0 + 1] = t1;
        }
      }
    }
  }
  // ---- C write: row = (lane>>4)*4 + reg, col = lane&15 ----
#pragma unroll
  for (int m = 0; m < 2; m++) {
#pragma unroll
    for (int r = 0; r < 4; r++) {
      int row = m0 + wrow + m * 16 + ((lane >> 4) << 2) + r;
      if (row < M) {
#pragma unroll
        for (int n = 0; n < 8; n++) {
          int col = n0 + n * 16 + (lane & 15);
          C[(long)row * Nc + col] = __float2bfloat16(acc[m][n][r]);
        }
      }
    }
  }
}

// ---- CSR build (both graphs in one pass; deg/fil [2N], rp [2(N+1)]) ----
__global__ void hist2_kernel(const int* __restrict__ trg0, const int* __restrict__ trg1,
                             int* __restrict__ deg, int E, int N) {
  int e = blockIdx.x * 256 + threadIdx.x;
  if (e < E) atomicAdd(&deg[trg0[e]], 1);
  else if (e < 2 * E) atomicAdd(&deg[N + trg1[e - E]], 1);
}

__global__ __launch_bounds__(1024) void scan_kernel(const int* __restrict__ degb,
                                                    int* __restrict__ rpb,
                                                    int* __restrict__ filb, int N) {
  const int* deg = degb + (long)blockIdx.x * N;
  int* row_ptr = rpb + (long)blockIdx.x * (N + 1);
  int* fil = filb + (long)blockIdx.x * N;
  __shared__ int sums[1024];
  int tid = threadIdx.x;
  int chunk = (N + 1023) >> 10;
  int start = tid * chunk;
  int end = start + chunk;
  if (start > N) start = N;
  if (end > N) end = N;
  int s = 0;
  for (int i = start; i < end; i++) s += deg[i];
  sums[tid] = s;
  __syncthreads();
  for (int off = 1; off < 1024; off <<= 1) {
    int add = (tid >= off) ? sums[tid - off] : 0;
    __syncthreads();
    sums[tid] += add;
    __syncthreads();
  }
  int run = (tid > 0) ? sums[tid - 1] : 0;
  for (int i = start; i < end; i++) {
    row_ptr[i] = run;
    fil[i] = run;
    run += deg[i];
  }
  if (tid == 0) row_ptr[N] = sums[1023];
}

__global__ void fill2_kernel(const int* __restrict__ src0, const int* __restrict__ trg0,
                             const int* __restrict__ src1, const int* __restrict__ trg1,
                             int* __restrict__ filb, int* __restrict__ colb, int E, int N) {
  int e = blockIdx.x * 256 + threadIdx.x;
  if (e < E) {
    int t = trg0[e];
    int pos = atomicAdd(&filb[t], 1);
    colb[pos] = src0[e];
  } else if (e < 2 * E) {
    int ee = e - E;
    int t = trg1[ee];
    int pos = atomicAdd(&filb[N + t], 1);
    colb[E + pos] = src1[ee];
  }
}

// ---------------------------------------------------------------------------
// GAT aggregation, fused single pass: out = (Σ_e ex_e · hp[src_e]) / (Σ_e ex_e).
// ONE wave per node (4 nodes per block). Lane c owns bytes [c*16,c*16+16) of
// the 1KB row (head h = c>>3). Edge srcs staged one-per-lane + __shfl
// broadcast; double-buffered 4-edge pipeline. blockIdx.y = type slot.
// mode 0: bf16 out[n*512 + o] = elu(sum)
// mode 1: float out[n*128 + o] = mean_h(sum)  (out base pre-offset per type)
// ---------------------------------------------------------------------------
__device__ __forceinline__ float exleaky(float v) {
  v = v > 0.f ? v : 0.2f * v;
  return __expf(v);
}

__global__ __launch_bounds__(256) void aggregate(AArg aa, int N, int mode) {
  const int ty = blockIdx.y;
  const bf16* __restrict__ hpb = aa.hp[ty];
  const float* __restrict__ svb = aa.sv[ty];
  const float* __restrict__ tvb = aa.tv[ty];
  const int* __restrict__ rp = aa.rp[ty];
  const int* __restrict__ colv = aa.col[ty];
  void* __restrict__ outp = aa.out[ty];
  const int wid = threadIdx.x >> 6;
  const int lane = threadIdx.x & 63;
  const int n = blockIdx.x * 4 + wid;
  if (n >= N) return;
  const int start = rp[n];
  const int deg = rp[n + 1] - start;
  const int h = lane >> 3;
  const float tvh = tvb[(long)n * 8 + h];
  const bf16* __restrict__ hpc = hpb + lane * 8;

  float acc[8] = {0.f, 0.f, 0.f, 0.f, 0.f, 0.f, 0.f, 0.f};
  float den = 1e-16f;

#define AG_LOAD(EB, V0, V1, V2, V3, Q0, Q1, Q2, Q3)                 \
  {                                                                 \
    int t0 = __shfl(mysrc, (EB) + 0), t1 = __shfl(mysrc, (EB) + 1); \
    int t2 = __shfl(mysrc, (EB) + 2), t3 = __shfl(mysrc, (EB) + 3); \
    V0 = *(const short8*)(hpc + (long)t0 * 512);                    \
    V1 = *(const short8*)(hpc + (long)t1 * 512);                    \
    V2 = *(const short8*)(hpc + (long)t2 * 512);                    \
    V3 = *(const short8*)(hpc + (long)t3 * 512);                    \
    Q0 = svb[(long)t0 * 8 + h];                                     \
    Q1 = svb[(long)t1 * 8 + h];                                     \
    Q2 = svb[(long)t2 * 8 + h];                                     \
    Q3 = svb[(long)t3 * 8 + h];                                     \
  }
#define AG_ACC(V0, V1, V2, V3, Q0, Q1, Q2, Q3)                      \
  {                                                                 \
    float a0 = exleaky(Q0 + tvh), a1 = exleaky(Q1 + tvh);           \
    float a2 = exleaky(Q2 + tvh), a3 = exleaky(Q3 + tvh);           \
    den += a0 + a1 + a2 + a3;                                       \
    _Pragma("unroll")                                               \
    for (int j = 0; j < 8; j++)                                     \
      acc[j] += a0 * bfbits2f(V0[j]) + a1 * bfbits2f(V1[j]) +       \
                a2 * bfbits2f(V2[j]) + a3 * bfbits2f(V3[j]);        \
  }

  for (int base = 0; base < deg; base += 64) {
    int cnt = deg - base;
    if (cnt > 64) cnt = 64;
    int mysrc = (lane < cnt) ? colv[start + base + lane] : 0;
    int nfull = cnt & ~3;
    if (nfull) {
      short8 v0, v1, v2, v3;
      float q0, q1, q2, q3;
      AG_LOAD(0, v0, v1, v2, v3, q0, q1, q2, q3);
      for (int e = 4; e < nfull; e += 4) {
        short8 w0 = v0, w1 = v1, w2 = v2, w3 = v3;
        float p0 = q0, p1 = q1, p2 = q2, p3 = q3;
        AG_LOAD(e, v0, v1, v2, v3, q0, q1, q2, q3);
        AG_ACC(w0, w1, w2, w3, p0, p1, p2, p3);
      }
      AG_ACC(v0, v1, v2, v3, q0, q1, q2, q3);
    }
    for (int e = nfull; e < cnt; e++) {
      int s0 = __shfl(mysrc, e);
      short8 v = *(const short8*)(hpc + (long)s0 * 512);
      float a = exleaky(svb[(long)s0 * 8 + h] + tvh);
      den += a;
#pragma unroll
      for (int j = 0; j < 8; j++) acc[j] += a * bfbits2f(v[j]);
    }
  }

  const float dinv = 1.f / den;
  if (mode == 0) {
    short8 o8;
#pragma unroll
    for (int j = 0; j < 8; j++) {
      float s = acc[j] * dinv;
      float ev = s > 0.f ? s : expm1f(s);
      o8[j] = f2bfbits(ev);
    }
    *(short8*)((bf16*)outp + (long)n * 512 + lane * 8) = o8;
  } else {
    float r[8];
#pragma unroll
    for (int j = 0; j < 8; j++) r[j] = acc[j] * dinv;
    // sum across the 8 lanes {q, q+8, ..., q+56} (q = lane&7): heads 0..7
#pragma unroll
    for (int m = 8; m <= 32; m <<= 1)
#pragma unroll
      for (int j = 0; j < 8; j++) r[j] += __shfl_xor(r[j], m);
    if (lane < 8) {
      float* o = (float*)outp + (long)n * 128 + lane * 8;
#pragma unroll
      for (int j = 0; j < 8; j++) o[j] = r[j] * 0.125f;
    }
  }
}

// favec[o] = (hemb1[0,:] @ W1) @ aw1[:,o]  — one 256-thread block.
__global__ __launch_bounds__(256) void favec2_kernel(const void* __restrict__ hemb1,
                                                     const void* __restrict__ W1,
                                                     const void* __restrict__ aw1,
                                                     float* __restrict__ favec,
                                                     const int* __restrict__ flag) {
  const int f32 = flag[0];
  __shared__ float s_h[128];
  __shared__ float s_r[256];
  __shared__ float part[4][64];
  const int tid = threadIdx.x;
  if (tid < 128) s_h[tid] = ldin(hemb1, tid, f32);
  __syncthreads();
  float r = 0.f;
  for (int i = 0; i < 128; i++) r += s_h[i] * ldin(W1, (long)i * 256 + tid, f32);
  s_r[tid] = r;
  __syncthreads();
  const int o = tid & 63;
  const int wv = tid >> 6;
  float acc = 0.f;
#pragma unroll
  for (int kk = 0; kk < 64; kk++) {
    int k = wv * 64 + kk;
    acc += s_r[k] * ldin(aw1, (long)k * 64 + o, f32);
  }
  part[wv][o] = acc;
  __syncthreads();
  if (tid < 64) favec[o] = part[0][o] + part[1][o] + part[2][o] + part[3][o];
}

// ---------------------------------------------------------------------------
// Semantic attention + FC + log_softmax. 16 nodes per 256-thread block.
// ---------------------------------------------------------------------------
#define FN 16
__global__ __launch_bounds__(256) void final_kernel(const float* __restrict__ ta,
                                                    const float* __restrict__ favec,
                                                    const void* __restrict__ aw2,
                                                    const void* __restrict__ am,
                                                    const void* __restrict__ fcw,
                                                    const void* __restrict__ fcb,
                                                    void* __restrict__ out, int N,
                                                    const int* __restrict__ flag) {
  const int f32 = flag[0];
  __shared__ float s_w[64 * 64];
  __shared__ float s_fc[384];
  __shared__ float s_misc[130];     // [0:64) favec, [64:128) am, [128:130) fcb
  __shared__ float s_ta[FN * 128];  // [ni][k][r] : ta0/ta1 interleaved
  const int tid = threadIdx.x;
  const int n0 = blockIdx.x * FN;
  for (int i = tid; i < 4096; i += 256) s_w[i] = ldin(aw2, i, f32);
  for (int i = tid; i < 384; i += 256) s_fc[i] = ldin(fcw, i, f32);
  if (tid < 64) s_misc[tid] = favec[tid];
  else if (tid < 128) s_misc[tid] = ldin(am, tid - 64, f32);
  else if (tid < 130) s_misc[tid] = ldin(fcb, tid - 128, f32);
  for (int idx = tid; idx < FN * 128; idx += 256) {
    int ni = idx >> 7;
    int j = idx & 127;
    int k = j >> 1, r = j & 1;
    int n = n0 + ni;
    s_ta[idx] = (n < N) ? ta[(long)n * 128 + r * 64 + k] : 0.f;
  }
  __syncthreads();
  const int o = tid & 63;
  const int wv = tid >> 6;
#pragma unroll
  for (int ni4 = 0; ni4 < 4; ni4++) {
    const int ni = wv * 4 + ni4;
    const int n = n0 + ni;
    if (n >= N) continue;
    const float* tb = &s_ta[ni * 128];
    float acc0 = s_misc[o], acc1 = acc0;
#pragma unroll 8
    for (int k = 0; k < 64; k++) {
      float2 t2 = *(const float2*)(tb + k * 2);  // broadcast (same addr)
      float w = s_w[k * 64 + o];
      acc0 += t2.x * w;
      acc1 += t2.y * w;
    }
    float ta0 = tb[o * 2];
    float ta1 = tb[o * 2 + 1];
    float amv = s_misc[64 + o];
    float p0 = tanhf(acc0) * amv;
    float p1 = tanhf(acc1) * amv;
#pragma unroll
    for (int off = 32; off > 0; off >>= 1) {
      p0 += __shfl_xor(p0, off);
      p1 += __shfl_xor(p1, off);
    }
    float mx = fmaxf(p0, p1);
    float e0 = __expf(p0 - mx), e1 = __expf(p1 - mx);
    float b0 = e0 / (e0 + e1), b1 = e1 / (e0 + e1);
    float fus = b0 * ta0 + b1 * ta1;
    float l0 = ta0 * s_fc[o * 2 + 0] + ta1 * s_fc[(64 + o) * 2 + 0] + fus * s_fc[(128 + o) * 2 + 0];
    float l1 = ta0 * s_fc[o * 2 + 1] + ta1 * s_fc[(64 + o) * 2 + 1] + fus * s_fc[(128 + o) * 2 + 1];
#pragma unroll
    for (int off = 32; off > 0; off >>= 1) {
      l0 += __shfl_xor(l0, off);
      l1 += __shfl_xor(l1, off);
    }
    if (o == 0) {
      l0 += s_misc[128];
      l1 += s_misc[129];
      float m2 = fmaxf(l0, l1);
      float lse = m2 + logf(__expf(l0 - m2) + __expf(l1 - m2));
      if (f32) {
        ((float*)out)[n * 2 + 0] = l0 - lse;
        ((float*)out)[n * 2 + 1] = l1 - lse;
      } else {
        ((bf16*)out)[n * 2 + 0] = __float2bfloat16(l0 - lse);
        ((bf16*)out)[n * 2 + 1] = __float2bfloat16(l1 - lse);
      }
    }
  }
}

extern "C" void kernel_launch(void* const* d_in, const int* in_sizes, int n_in,
                              void* d_out, int out_size, void* d_ws, size_t ws_size,
                              hipStream_t stream) {
  constexpr int N = 20000, E = 320000, H = 8, F0 = 128, FU = 256, FO = 64;
  const void* hemb[2] = {d_in[0], d_in[1]};
  const void* W[2] = {d_in[2], d_in[3]};
  const void* gw[2][2] = {{d_in[4], d_in[7]}, {d_in[10], d_in[13]}};
  const void* gasrc[2][2] = {{d_in[5], d_in[8]}, {d_in[11], d_in[14]}};
  const void* gatrg[2][2] = {{d_in[6], d_in[9]}, {d_in[12], d_in[15]}};
  const void* aw1 = d_in[16];
  const void* aw2 = d_in[17];
  const void* am = d_in[18];
  const void* fcw = d_in[19];
  const void* fcb = d_in[20];
  const int* edge[2] = {(const int*)d_in[21], (const int*)d_in[22]};

  const size_t szWg = (size_t)F0 * 512 * 2;   // 128x512 bf16 per type
  const size_t szHp = (size_t)N * 512 * 2;
  const size_t szSv = (size_t)N * 8 * 4;
  size_t need = 0;
  auto addsz = [&](size_t b) { need += (b + 255) & ~(size_t)255; };
  addsz(4);
  addsz(szWg * 2);
  addsz(szHp * 2); addsz(szHp * 2);
  addsz(szSv * 2); addsz(szSv * 2);
  addsz((size_t)N * 128 * 4); addsz(256);
  addsz((size_t)2 * N * 4); addsz((size_t)2 * (N + 1) * 4);
  addsz((size_t)2 * N * 4); addsz((size_t)2 * E * 4);
  const bool batched = (ws_size >= need + 4096);
  const int TB = batched ? 2 : 1;

  char* p = (char*)d_ws;
  auto alloc = [&](size_t bytes) -> void* {
    void* r = (void*)p;
    p += (bytes + 255) & ~(size_t)255;
    return r;
  };
  int* flag = (int*)alloc(4);
  bf16* wg = (bf16*)alloc(szWg * 2);          // always 2 slots (tiny)
  bf16* hp = (bf16*)alloc(szHp * TB);
  bf16* xbuf = (bf16*)alloc(szHp * TB);
  float* sv = (float*)alloc(szSv * TB);
  float* tv = (float*)alloc(szSv * TB);
  float* ta = (float*)alloc((size_t)N * 128 * 4);
  float* favec = (float*)alloc(256);
  int* degb = (int*)alloc((size_t)2 * N * 4);
  int* rpb = (int*)alloc((size_t)2 * (N + 1) * 4);
  int* filb = (int*)alloc((size_t)2 * N * 4);
  int* colb = (int*)alloc((size_t)2 * E * 4);

  detect_kernel<<<1, 64, 0, stream>>>(hemb[0], flag);

  // CSR build for both graphs in one pass
  hipMemsetAsync(degb, 0, (size_t)2 * N * 4, stream);
  hist2_kernel<<<(2 * E + 255) / 256, 256, 0, stream>>>(edge[0] + E, edge[1] + E, degb, E, N);
  scan_kernel<<<2, 1024, 0, stream>>>(degb, rpb, filb, N);
  fill2_kernel<<<(2 * E + 255) / 256, 256, 0, stream>>>(edge[0], edge[0] + E,
                                                        edge[1], edge[1] + E, filb, colb, E, N);

  // favec from inputs directly (trans not materialized)
  favec2_kernel<<<1, 256, 0, stream>>>(hemb[1], W[1], aw1, favec, flag);

  // Wg[t] = W[t] @ gw[t][0] : [128][512] bf16 ws (both types in one launch)
  {
    GArg gW{};
    for (int i = 0; i < 2; i++) {
      gW.A[i] = W[i]; gW.B[i] = gw[i][0]; gW.C[i] = wg + (size_t)i * F0 * 512;
      gW.sa[i] = nullptr; gW.sb[i] = nullptr; gW.sv[i] = nullptr; gW.tv[i] = nullptr;
    }
    gemm_mfma<<<dim3(1, (H * FO) / GBN, 2), 256, 0, stream>>>(gW, 1, 1, F0, FU, H * FO, flag);
  }

  const int gmx = (N + GBM - 1) / GBM;  // 157
  const int npass = batched ? 1 : 2;
  const int TC = batched ? 2 : 1;

  auto hpP = [&](int b) { return hp + (size_t)b * N * 512; };
  auto xbufP = [&](int b) { return xbuf + (size_t)b * N * 512; };
  auto svP = [&](int b) { return sv + (size_t)b * N * 8; };
  auto tvP = [&](int b) { return tv + (size_t)b * N * 8; };

  for (int pass = 0; pass < npass; pass++) {
    int types[2] = {batched ? 0 : pass, batched ? 1 : pass};
    int bufs[2] = {0, batched ? 1 : 0};

    // hp layer 0 (fused trans): A = hemb (input, K=128), B = Wg (ws bf16)
    GArg g1{};
    for (int i = 0; i < TC; i++) {
      int t = types[i], b = bufs[i];
      g1.A[i] = hemb[t]; g1.B[i] = wg + (size_t)t * F0 * 512; g1.C[i] = hpP(b);
      g1.sa[i] = gasrc[t][0]; g1.sb[i] = gatrg[t][0]; g1.sv[i] = svP(b); g1.tv[i] = tvP(b);
    }
    gemm_mfma<<<dim3(gmx, (H * FO) / GBN, TC), 256, 0, stream>>>(g1, 1, 2, N, F0, H * FO, flag);

    AArg a0{};
    for (int i = 0; i < TC; i++) {
      int t = types[i], b = bufs[i];
      a0.hp[i] = hpP(b); a0.sv[i] = svP(b); a0.tv[i] = tvP(b);
      a0.rp[i] = rpb + (size_t)t * (N + 1); a0.col[i] = colb + (size_t)t * E;
      a0.out[i] = xbufP(b);
    }
    aggregate<<<dim3((N + 3) / 4, TC), 256, 0, stream>>>(a0, N, 0);

    GArg g2{};
    for (int i = 0; i < TC; i++) {
      int t = types[i], b = bufs[i];
      g2.A[i] = xbufP(b); g2.B[i] = gw[t][1]; g2.C[i] = hpP(b);
      g2.sa[i] = gasrc[t][1]; g2.sb[i] = gatrg[t][1]; g2.sv[i] = svP(b); g2.tv[i] = tvP(b);
    }
    gemm_mfma<<<dim3(gmx, (H * FO) / GBN, TC), 256, 0, stream>>>(g2, 0, 1, N, H * FO, H * FO, flag);

    AArg a1{};
    for (int i = 0; i < TC; i++) {
      int t = types[i], b = bufs[i];
      a1.hp[i] = hpP(b); a1.sv[i] = svP(b); a1.tv[i] = tvP(b);
      a1.rp[i] = rpb + (size_t)t * (N + 1); a1.col[i] = colb + (size_t)t * E;
      a1.out[i] = ta + (size_t)t * FO;
    }
    aggregate<<<dim3((N + 3) / 4, TC), 256, 0, stream>>>(a1, N, 1);
  }

  final_kernel<<<(N + FN - 1) / FN, 256, 0, stream>>>(ta, favec, aw2, am, fcw, fcb, d_out, N, flag);
}

// Round 11
// 584.570 us; speedup vs baseline: 1.0078x; 1.0078x over previous
//
#include <hip/hip_runtime.h>
#include <hip/hip_bf16.h>

// ---------------------------------------------------------------------------
// HetergatWOConcatFeat — round 12:
//  - GEMM: BN=128 kept (A re-read halved, FETCH 169->89MB confirmed r11) but
//    8 waves / 512 threads per block: per-wave tile back to 32x64 (acc[2][4],
//    ~52 VGPR — round-11's 4-wave acc[2][8] spilled at VGPR_Count=84 and ran
//    at 25% occupancy / 1.2TB/s). Wave w: rows (w>>1)*32, cols (w&1)*64.
//    Fused-st: wave covers head 2*blockIdx.y + (w&1).
//  - Everything else unchanged from round 11.
// ---------------------------------------------------------------------------

typedef __hip_bfloat16 bf16;
typedef __attribute__((ext_vector_type(8))) short short8;
typedef __attribute__((ext_vector_type(4))) float f32x4;

__device__ __forceinline__ float bf2f(bf16 v) { return __bfloat162float(v); }
__device__ __forceinline__ float ldin(const void* p, long i, int f32) {
  return f32 ? ((const float*)p)[i] : bf2f(((const bf16*)p)[i]);
}
__device__ __forceinline__ short f2bfbits(float f) {
  bf16 h = __float2bfloat16(f);
  return *reinterpret_cast<short*>(&h);
}
__device__ __forceinline__ float bfbits2f(short b) {
  unsigned u = ((unsigned)(unsigned short)b) << 16;
  return __uint_as_float(u);
}

struct GArg {
  const void* A[2];
  const void* B[2];
  bf16* C[2];
  const void* sa[2];
  const void* sb[2];
  float* sv[2];
  float* tv[2];
};

struct AArg {
  const bf16* hp[2];
  const float* sv[2];
  const float* tv[2];
  const int* rp[2];
  const int* col[2];
  void* out[2];
};

// Detect input dtype: read first 2048 elements of hemb0 as bf16. If the data
// is really f32, the mantissa halves decode to huge/NaN values.
__global__ __launch_bounds__(64) void detect_kernel(const void* __restrict__ x,
                                                    int* __restrict__ flag) {
  int tid = threadIdx.x;
  float m = 0.f;
  for (int i = tid; i < 2048; i += 64) {
    float v = fabsf(bf2f(((const bf16*)x)[i]));
    if (!(v <= 1e3f)) v = 1e9f;  // NaN/Inf/big -> force detect
    m = fmaxf(m, v);
  }
#pragma unroll
  for (int off = 32; off; off >>= 1) m = fmaxf(m, __shfl_xor(m, off));
  if (tid == 0) flag[0] = (m > 1e3f) ? 1 : 0;
}

// ---------------------------------------------------------------------------
// MFMA GEMM: C[M][Nc] (bf16, row-major) = A[M][K] @ B[K][Nc], fp32 accum.
// amode: 0 = A ws bf16 row-major; 1 = A input tensor (dtype by flag).
// bmode: 0 = B row-major [K][Nc] input; 1 = B head-blocked [H][K][64] input;
//        2 = B row-major [K][Nc] WS bf16 (flag-independent).
// Tile: BM=128, BN=128, BK=64. 512 threads = 8 waves; wave w owns rows
// (w>>1)*32 x cols (w&1)*64 -> acc[2][4] (32 VGPR). LDS 32KB, XOR-swizzled.
// blockIdx.z selects the type-slot. Fused st when sv[z] != null (Nc=512:
// wave covers head 2*blockIdx.y + (w&1)).
// ---------------------------------------------------------------------------
#define GBM 128
#define GBN 128
#define GBK 64

__device__ __forceinline__ int swz(int row, int kbyte) {
  return row * 128 + (kbyte ^ ((row & 7) << 4));
}

__global__ __launch_bounds__(512) void gemm_mfma(GArg g, int amode, int bmode,
                                                 int M, int K, int Nc,
                                                 const int* __restrict__ flag) {
  __shared__ bf16 As[GBM * GBK];
  __shared__ bf16 Bs[GBN * GBK];
  const int z = blockIdx.z;
  const void* __restrict__ A = g.A[z];
  const void* __restrict__ B = g.B[z];
  bf16* __restrict__ C = g.C[z];
  const void* stasrc = g.sa[z];
  const void* statrg = g.sb[z];
  float* svp = g.sv[z];
  float* tvp = g.tv[z];
  const int f32 = flag[0];
  const int af32 = (amode == 1) ? f32 : 0;
  const int bf32 = (bmode == 2) ? 0 : f32;
  const int m0 = blockIdx.x * GBM;
  const int n0 = blockIdx.y * GBN;
  const int tid = threadIdx.x;
  const int lane = tid & 63;
  const int w = tid >> 6;            // 0..7
  const int wrow = (w >> 1) * 32;    // 0,32,64,96
  const int wcol = (w & 1) * 64;     // 0 or 64

  f32x4 acc[2][4];
#pragma unroll
  for (int m = 0; m < 2; m++)
#pragma unroll
    for (int n = 0; n < 4; n++)
#pragma unroll
      for (int r = 0; r < 4; r++) acc[m][n][r] = 0.f;

  for (int kt = 0; kt < K; kt += GBK) {
    // ---- stage A: 128 rows x 64 k (bf16), 1024 16B slots, 2 per thread ----
#pragma unroll
    for (int j = 0; j < 2; j++) {
      int idx = tid + j * 512;       // 0..1023
      int row = idx >> 3;            // 0..127
      int ks = idx & 7;              // 16B slot within row
      int gm = m0 + row;
      short8 v;
#pragma unroll
      for (int e = 0; e < 8; e++) v[e] = 0;
      if (gm < M) {
        long base = (long)gm * K + kt + ks * 8;
        if (!af32) {
          v = *(const short8*)((const bf16*)A + base);
        } else {
          const float* Af = (const float*)A + base;
          float4 x0 = *(const float4*)Af;
          float4 x1 = *(const float4*)(Af + 4);
          v[0] = f2bfbits(x0.x); v[1] = f2bfbits(x0.y);
          v[2] = f2bfbits(x0.z); v[3] = f2bfbits(x0.w);
          v[4] = f2bfbits(x1.x); v[5] = f2bfbits(x1.y);
          v[6] = f2bfbits(x1.z); v[7] = f2bfbits(x1.w);
        }
      }
      *(short8*)((char*)As + swz(row, ks * 16)) = v;
    }
    // ---- stage B transposed: Bs[col][k], 128 cols x 64 k, 2 per thread ----
#pragma unroll
    for (int j = 0; j < 2; j++) {
      int idx = tid + j * 512;       // 0..1023
      int col = idx >> 3;            // 0..127
      int ks = idx & 7;
      int k = kt + ks * 8;
      int gcol = n0 + col;
      long base;
      int cstr;
      if (bmode == 1) { base = ((long)(gcol >> 6) * K + k) * 64 + (gcol & 63); cstr = 64; }
      else { base = (long)k * Nc + gcol; cstr = Nc; }
      short8 v;
      if (bf32) {
        const float* Bf = (const float*)B;
#pragma unroll
        for (int e = 0; e < 8; e++) v[e] = f2bfbits(Bf[base + (long)e * cstr]);
      } else {
        const bf16* Bh = (const bf16*)B;
#pragma unroll
        for (int e = 0; e < 8; e++) v[e] = *(const short*)&Bh[base + (long)e * cstr];
      }
      *(short8*)((char*)Bs + swz(col, ks * 16)) = v;
    }
    __syncthreads();
    // ---- compute: 2 k-halves of 32, per wave 2x4 fragments ----
#pragma unroll
    for (int kh = 0; kh < 2; kh++) {
      int klane = kh * 64 + ((lane >> 4) << 4);  // byte offset of k within row
      short8 af[2], bfr[4];
#pragma unroll
      for (int m = 0; m < 2; m++) {
        int row = wrow + m * 16 + (lane & 15);
        af[m] = *(const short8*)((const char*)As + swz(row, klane));
      }
#pragma unroll
      for (int n = 0; n < 4; n++) {
        int col = wcol + n * 16 + (lane & 15);
        bfr[n] = *(const short8*)((const char*)Bs + swz(col, klane));
      }
#pragma unroll
      for (int m = 0; m < 2; m++)
#pragma unroll
        for (int n = 0; n < 4; n++)
          acc[m][n] = __builtin_amdgcn_mfma_f32_16x16x32_bf16(af[m], bfr[n], acc[m][n], 0, 0, 0);
    }
    __syncthreads();
  }
  // ---- fused st: s/t from fp32 acc. Wave covers head 2*blockIdx.y+(w&1) ----
  if (svp) {
    const int h = blockIdx.y * 2 + (w & 1);
    const int cl = lane & 15;
    float av[4], bv[4];
#pragma unroll
    for (int n = 0; n < 4; n++) {
      av[n] = ldin(stasrc, h * 64 + n * 16 + cl, f32);
      bv[n] = ldin(statrg, h * 64 + n * 16 + cl, f32);
    }
#pragma unroll
    for (int m = 0; m < 2; m++) {
#pragma unroll
      for (int r = 0; r < 4; r++) {
        float s = 0.f, t = 0.f;
#pragma unroll
        for (int n = 0; n < 4; n++) {
          s += acc[m][n][r] * av[n];
          t += acc[m][n][r] * bv[n];
        }
#pragma unroll
        for (int off = 1; off <= 8; off <<= 1) {
          s += __shfl_xor(s, off);
          t += __shfl_xor(t, off);
        }
        int row = m0 + wrow + m * 16 + ((lane >> 4) << 2) + r;
        if (cl == 0 && row < M) {
          svp[(long)row * 8 + h] = s;
          tvp[(long)row * 8 + h] = t;
        }
      }
    }
  }
  // ---- C write: row = (lane>>4)*4 + reg, col = lane&15 ----
#pragma unroll
  for (int m = 0; m < 2; m++) {
#pragma unroll
    for (int r = 0; r < 4; r++) {
      int row = m0 + wrow + m * 16 + ((lane >> 4) << 2) + r;
      if (row < M) {
#pragma unroll
        for (int n = 0; n < 4; n++) {
          int col = n0 + wcol + n * 16 + (lane & 15);
          C[(long)row * Nc + col] = __float2bfloat16(acc[m][n][r]);
        }
      }
    }
  }
}

// ---- CSR build (both graphs in one pass; deg/fil [2N], rp [2(N+1)]) ----
__global__ void hist2_kernel(const int* __restrict__ trg0, const int* __restrict__ trg1,
                             int* __restrict__ deg, int E, int N) {
  int e = blockIdx.x * 256 + threadIdx.x;
  if (e < E) atomicAdd(&deg[trg0[e]], 1);
  else if (e < 2 * E) atomicAdd(&deg[N + trg1[e - E]], 1);
}

__global__ __launch_bounds__(1024) void scan_kernel(const int* __restrict__ degb,
                                                    int* __restrict__ rpb,
                                                    int* __restrict__ filb, int N) {
  const int* deg = degb + (long)blockIdx.x * N;
  int* row_ptr = rpb + (long)blockIdx.x * (N + 1);
  int* fil = filb + (long)blockIdx.x * N;
  __shared__ int sums[1024];
  int tid = threadIdx.x;
  int chunk = (N + 1023) >> 10;
  int start = tid * chunk;
  int end = start + chunk;
  if (start > N) start = N;
  if (end > N) end = N;
  int s = 0;
  for (int i = start; i < end; i++) s += deg[i];
  sums[tid] = s;
  __syncthreads();
  for (int off = 1; off < 1024; off <<= 1) {
    int add = (tid >= off) ? sums[tid - off] : 0;
    __syncthreads();
    sums[tid] += add;
    __syncthreads();
  }
  int run = (tid > 0) ? sums[tid - 1] : 0;
  for (int i = start; i < end; i++) {
    row_ptr[i] = run;
    fil[i] = run;
    run += deg[i];
  }
  if (tid == 0) row_ptr[N] = sums[1023];
}

__global__ void fill2_kernel(const int* __restrict__ src0, const int* __restrict__ trg0,
                             const int* __restrict__ src1, const int* __restrict__ trg1,
                             int* __restrict__ filb, int* __restrict__ colb, int E, int N) {
  int e = blockIdx.x * 256 + threadIdx.x;
  if (e < E) {
    int t = trg0[e];
    int pos = atomicAdd(&filb[t], 1);
    colb[pos] = src0[e];
  } else if (e < 2 * E) {
    int ee = e - E;
    int t = trg1[ee];
    int pos = atomicAdd(&filb[N + t], 1);
    colb[E + pos] = src1[ee];
  }
}

// ---------------------------------------------------------------------------
// GAT aggregation, fused single pass: out = (Σ_e ex_e · hp[src_e]) / (Σ_e ex_e).
// ONE wave per node (4 nodes per block). Lane c owns bytes [c*16,c*16+16) of
// the 1KB row (head h = c>>3). Edge srcs staged one-per-lane + __shfl
// broadcast; double-buffered 4-edge pipeline. blockIdx.y = type slot.
// mode 0: bf16 out[n*512 + o] = elu(sum)
// mode 1: float out[n*128 + o] = mean_h(sum)  (out base pre-offset per type)
// ---------------------------------------------------------------------------
__device__ __forceinline__ float exleaky(float v) {
  v = v > 0.f ? v : 0.2f * v;
  return __expf(v);
}

__global__ __launch_bounds__(256) void aggregate(AArg aa, int N, int mode) {
  const int ty = blockIdx.y;
  const bf16* __restrict__ hpb = aa.hp[ty];
  const float* __restrict__ svb = aa.sv[ty];
  const float* __restrict__ tvb = aa.tv[ty];
  const int* __restrict__ rp = aa.rp[ty];
  const int* __restrict__ colv = aa.col[ty];
  void* __restrict__ outp = aa.out[ty];
  const int wid = threadIdx.x >> 6;
  const int lane = threadIdx.x & 63;
  const int n = blockIdx.x * 4 + wid;
  if (n >= N) return;
  const int start = rp[n];
  const int deg = rp[n + 1] - start;
  const int h = lane >> 3;
  const float tvh = tvb[(long)n * 8 + h];
  const bf16* __restrict__ hpc = hpb + lane * 8;

  float acc[8] = {0.f, 0.f, 0.f, 0.f, 0.f, 0.f, 0.f, 0.f};
  float den = 1e-16f;

#define AG_LOAD(EB, V0, V1, V2, V3, Q0, Q1, Q2, Q3)                 \
  {                                                                 \
    int t0 = __shfl(mysrc, (EB) + 0), t1 = __shfl(mysrc, (EB) + 1); \
    int t2 = __shfl(mysrc, (EB) + 2), t3 = __shfl(mysrc, (EB) + 3); \
    V0 = *(const short8*)(hpc + (long)t0 * 512);                    \
    V1 = *(const short8*)(hpc + (long)t1 * 512);                    \
    V2 = *(const short8*)(hpc + (long)t2 * 512);                    \
    V3 = *(const short8*)(hpc + (long)t3 * 512);                    \
    Q0 = svb[(long)t0 * 8 + h];                                     \
    Q1 = svb[(long)t1 * 8 + h];                                     \
    Q2 = svb[(long)t2 * 8 + h];                                     \
    Q3 = svb[(long)t3 * 8 + h];                                     \
  }
#define AG_ACC(V0, V1, V2, V3, Q0, Q1, Q2, Q3)                      \
  {                                                                 \
    float a0 = exleaky(Q0 + tvh), a1 = exleaky(Q1 + tvh);           \
    float a2 = exleaky(Q2 + tvh), a3 = exleaky(Q3 + tvh);           \
    den += a0 + a1 + a2 + a3;                                       \
    _Pragma("unroll")                                               \
    for (int j = 0; j < 8; j++)                                     \
      acc[j] += a0 * bfbits2f(V0[j]) + a1 * bfbits2f(V1[j]) +       \
                a2 * bfbits2f(V2[j]) + a3 * bfbits2f(V3[j]);        \
  }

  for (int base = 0; base < deg; base += 64) {
    int cnt = deg - base;
    if (cnt > 64) cnt = 64;
    int mysrc = (lane < cnt) ? colv[start + base + lane] : 0;
    int nfull = cnt & ~3;
    if (nfull) {
      short8 v0, v1, v2, v3;
      float q0, q1, q2, q3;
      AG_LOAD(0, v0, v1, v2, v3, q0, q1, q2, q3);
      for (int e = 4; e < nfull; e += 4) {
        short8 w0 = v0, w1 = v1, w2 = v2, w3 = v3;
        float p0 = q0, p1 = q1, p2 = q2, p3 = q3;
        AG_LOAD(e, v0, v1, v2, v3, q0, q1, q2, q3);
        AG_ACC(w0, w1, w2, w3, p0, p1, p2, p3);
      }
      AG_ACC(v0, v1, v2, v3, q0, q1, q2, q3);
    }
    for (int e = nfull; e < cnt; e++) {
      int s0 = __shfl(mysrc, e);
      short8 v = *(const short8*)(hpc + (long)s0 * 512);
      float a = exleaky(svb[(long)s0 * 8 + h] + tvh);
      den += a;
#pragma unroll
      for (int j = 0; j < 8; j++) acc[j] += a * bfbits2f(v[j]);
    }
  }

  const float dinv = 1.f / den;
  if (mode == 0) {
    short8 o8;
#pragma unroll
    for (int j = 0; j < 8; j++) {
      float s = acc[j] * dinv;
      float ev = s > 0.f ? s : expm1f(s);
      o8[j] = f2bfbits(ev);
    }
    *(short8*)((bf16*)outp + (long)n * 512 + lane * 8) = o8;
  } else {
    float r[8];
#pragma unroll
    for (int j = 0; j < 8; j++) r[j] = acc[j] * dinv;
    // sum across the 8 lanes {q, q+8, ..., q+56} (q = lane&7): heads 0..7
#pragma unroll
    for (int m = 8; m <= 32; m <<= 1)
#pragma unroll
      for (int j = 0; j < 8; j++) r[j] += __shfl_xor(r[j], m);
    if (lane < 8) {
      float* o = (float*)outp + (long)n * 128 + lane * 8;
#pragma unroll
      for (int j = 0; j < 8; j++) o[j] = r[j] * 0.125f;
    }
  }
}

// favec[o] = (hemb1[0,:] @ W1) @ aw1[:,o]  — one 256-thread block.
__global__ __launch_bounds__(256) void favec2_kernel(const void* __restrict__ hemb1,
                                                     const void* __restrict__ W1,
                                                     const void* __restrict__ aw1,
                                                     float* __restrict__ favec,
                                                     const int* __restrict__ flag) {
  const int f32 = flag[0];
  __shared__ float s_h[128];
  __shared__ float s_r[256];
  __shared__ float part[4][64];
  const int tid = threadIdx.x;
  if (tid < 128) s_h[tid] = ldin(hemb1, tid, f32);
  __syncthreads();
  float r = 0.f;
  for (int i = 0; i < 128; i++) r += s_h[i] * ldin(W1, (long)i * 256 + tid, f32);
  s_r[tid] = r;
  __syncthreads();
  const int o = tid & 63;
  const int wv = tid >> 6;
  float acc = 0.f;
#pragma unroll
  for (int kk = 0; kk < 64; kk++) {
    int k = wv * 64 + kk;
    acc += s_r[k] * ldin(aw1, (long)k * 64 + o, f32);
  }
  part[wv][o] = acc;
  __syncthreads();
  if (tid < 64) favec[o] = part[0][o] + part[1][o] + part[2][o] + part[3][o];
}

// ---------------------------------------------------------------------------
// Semantic attention + FC + log_softmax. 16 nodes per 256-thread block.
// ---------------------------------------------------------------------------
#define FN 16
__global__ __launch_bounds__(256) void final_kernel(const float* __restrict__ ta,
                                                    const float* __restrict__ favec,
                                                    const void* __restrict__ aw2,
                                                    const void* __restrict__ am,
                                                    const void* __restrict__ fcw,
                                                    const void* __restrict__ fcb,
                                                    void* __restrict__ out, int N,
                                                    const int* __restrict__ flag) {
  const int f32 = flag[0];
  __shared__ float s_w[64 * 64];
  __shared__ float s_fc[384];
  __shared__ float s_misc[130];     // [0:64) favec, [64:128) am, [128:130) fcb
  __shared__ float s_ta[FN * 128];  // [ni][k][r] : ta0/ta1 interleaved
  const int tid = threadIdx.x;
  const int n0 = blockIdx.x * FN;
  for (int i = tid; i < 4096; i += 256) s_w[i] = ldin(aw2, i, f32);
  for (int i = tid; i < 384; i += 256) s_fc[i] = ldin(fcw, i, f32);
  if (tid < 64) s_misc[tid] = favec[tid];
  else if (tid < 128) s_misc[tid] = ldin(am, tid - 64, f32);
  else if (tid < 130) s_misc[tid] = ldin(fcb, tid - 128, f32);
  for (int idx = tid; idx < FN * 128; idx += 256) {
    int ni = idx >> 7;
    int j = idx & 127;
    int k = j >> 1, r = j & 1;
    int n = n0 + ni;
    s_ta[idx] = (n < N) ? ta[(long)n * 128 + r * 64 + k] : 0.f;
  }
  __syncthreads();
  const int o = tid & 63;
  const int wv = tid >> 6;
#pragma unroll
  for (int ni4 = 0; ni4 < 4; ni4++) {
    const int ni = wv * 4 + ni4;
    const int n = n0 + ni;
    if (n >= N) continue;
    const float* tb = &s_ta[ni * 128];
    float acc0 = s_misc[o], acc1 = acc0;
#pragma unroll 8
    for (int k = 0; k < 64; k++) {
      float2 t2 = *(const float2*)(tb + k * 2);  // broadcast (same addr)
      float w = s_w[k * 64 + o];
      acc0 += t2.x * w;
      acc1 += t2.y * w;
    }
    float ta0 = tb[o * 2];
    float ta1 = tb[o * 2 + 1];
    float amv = s_misc[64 + o];
    float p0 = tanhf(acc0) * amv;
    float p1 = tanhf(acc1) * amv;
#pragma unroll
    for (int off = 32; off > 0; off >>= 1) {
      p0 += __shfl_xor(p0, off);
      p1 += __shfl_xor(p1, off);
    }
    float mx = fmaxf(p0, p1);
    float e0 = __expf(p0 - mx), e1 = __expf(p1 - mx);
    float b0 = e0 / (e0 + e1), b1 = e1 / (e0 + e1);
    float fus = b0 * ta0 + b1 * ta1;
    float l0 = ta0 * s_fc[o * 2 + 0] + ta1 * s_fc[(64 + o) * 2 + 0] + fus * s_fc[(128 + o) * 2 + 0];
    float l1 = ta0 * s_fc[o * 2 + 1] + ta1 * s_fc[(64 + o) * 2 + 1] + fus * s_fc[(128 + o) * 2 + 1];
#pragma unroll
    for (int off = 32; off > 0; off >>= 1) {
      l0 += __shfl_xor(l0, off);
      l1 += __shfl_xor(l1, off);
    }
    if (o == 0) {
      l0 += s_misc[128];
      l1 += s_misc[129];
      float m2 = fmaxf(l0, l1);
      float lse = m2 + logf(__expf(l0 - m2) + __expf(l1 - m2));
      if (f32) {
        ((float*)out)[n * 2 + 0] = l0 - lse;
        ((float*)out)[n * 2 + 1] = l1 - lse;
      } else {
        ((bf16*)out)[n * 2 + 0] = __float2bfloat16(l0 - lse);
        ((bf16*)out)[n * 2 + 1] = __float2bfloat16(l1 - lse);
      }
    }
  }
}

extern "C" void kernel_launch(void* const* d_in, const int* in_sizes, int n_in,
                              void* d_out, int out_size, void* d_ws, size_t ws_size,
                              hipStream_t stream) {
  constexpr int N = 20000, E = 320000, H = 8, F0 = 128, FU = 256, FO = 64;
  const void* hemb[2] = {d_in[0], d_in[1]};
  const void* W[2] = {d_in[2], d_in[3]};
  const void* gw[2][2] = {{d_in[4], d_in[7]}, {d_in[10], d_in[13]}};
  const void* gasrc[2][2] = {{d_in[5], d_in[8]}, {d_in[11], d_in[14]}};
  const void* gatrg[2][2] = {{d_in[6], d_in[9]}, {d_in[12], d_in[15]}};
  const void* aw1 = d_in[16];
  const void* aw2 = d_in[17];
  const void* am = d_in[18];
  const void* fcw = d_in[19];
  const void* fcb = d_in[20];
  const int* edge[2] = {(const int*)d_in[21], (const int*)d_in[22]};

  const size_t szWg = (size_t)F0 * 512 * 2;   // 128x512 bf16 per type
  const size_t szHp = (size_t)N * 512 * 2;
  const size_t szSv = (size_t)N * 8 * 4;
  size_t need = 0;
  auto addsz = [&](size_t b) { need += (b + 255) & ~(size_t)255; };
  addsz(4);
  addsz(szWg * 2);
  addsz(szHp * 2); addsz(szHp * 2);
  addsz(szSv * 2); addsz(szSv * 2);
  addsz((size_t)N * 128 * 4); addsz(256);
  addsz((size_t)2 * N * 4); addsz((size_t)2 * (N + 1) * 4);
  addsz((size_t)2 * N * 4); addsz((size_t)2 * E * 4);
  const bool batched = (ws_size >= need + 4096);
  const int TB = batched ? 2 : 1;

  char* p = (char*)d_ws;
  auto alloc = [&](size_t bytes) -> void* {
    void* r = (void*)p;
    p += (bytes + 255) & ~(size_t)255;
    return r;
  };
  int* flag = (int*)alloc(4);
  bf16* wg = (bf16*)alloc(szWg * 2);          // always 2 slots (tiny)
  bf16* hp = (bf16*)alloc(szHp * TB);
  bf16* xbuf = (bf16*)alloc(szHp * TB);
  float* sv = (float*)alloc(szSv * TB);
  float* tv = (float*)alloc(szSv * TB);
  float* ta = (float*)alloc((size_t)N * 128 * 4);
  float* favec = (float*)alloc(256);
  int* degb = (int*)alloc((size_t)2 * N * 4);
  int* rpb = (int*)alloc((size_t)2 * (N + 1) * 4);
  int* filb = (int*)alloc((size_t)2 * N * 4);
  int* colb = (int*)alloc((size_t)2 * E * 4);

  detect_kernel<<<1, 64, 0, stream>>>(hemb[0], flag);

  // CSR build for both graphs in one pass
  hipMemsetAsync(degb, 0, (size_t)2 * N * 4, stream);
  hist2_kernel<<<(2 * E + 255) / 256, 256, 0, stream>>>(edge[0] + E, edge[1] + E, degb, E, N);
  scan_kernel<<<2, 1024, 0, stream>>>(degb, rpb, filb, N);
  fill2_kernel<<<(2 * E + 255) / 256, 256, 0, stream>>>(edge[0], edge[0] + E,
                                                        edge[1], edge[1] + E, filb, colb, E, N);

  // favec from inputs directly (trans not materialized)
  favec2_kernel<<<1, 256, 0, stream>>>(hemb[1], W[1], aw1, favec, flag);

  // Wg[t] = W[t] @ gw[t][0] : [128][512] bf16 ws (both types in one launch)
  {
    GArg gW{};
    for (int i = 0; i < 2; i++) {
      gW.A[i] = W[i]; gW.B[i] = gw[i][0]; gW.C[i] = wg + (size_t)i * F0 * 512;
      gW.sa[i] = nullptr; gW.sb[i] = nullptr; gW.sv[i] = nullptr; gW.tv[i] = nullptr;
    }
    gemm_mfma<<<dim3(1, (H * FO) / GBN, 2), 512, 0, stream>>>(gW, 1, 1, F0, FU, H * FO, flag);
  }

  const int gmx = (N + GBM - 1) / GBM;  // 157
  const int npass = batched ? 1 : 2;
  const int TC = batched ? 2 : 1;

  auto hpP = [&](int b) { return hp + (size_t)b * N * 512; };
  auto xbufP = [&](int b) { return xbuf + (size_t)b * N * 512; };
  auto svP = [&](int b) { return sv + (size_t)b * N * 8; };
  auto tvP = [&](int b) { return tv + (size_t)b * N * 8; };

  for (int pass = 0; pass < npass; pass++) {
    int types[2] = {batched ? 0 : pass, batched ? 1 : pass};
    int bufs[2] = {0, batched ? 1 : 0};

    // hp layer 0 (fused trans): A = hemb (input, K=128), B = Wg (ws bf16)
    GArg g1{};
    for (int i = 0; i < TC; i++) {
      int t = types[i], b = bufs[i];
      g1.A[i] = hemb[t]; g1.B[i] = wg + (size_t)t * F0 * 512; g1.C[i] = hpP(b);
      g1.sa[i] = gasrc[t][0]; g1.sb[i] = gatrg[t][0]; g1.sv[i] = svP(b); g1.tv[i] = tvP(b);
    }
    gemm_mfma<<<dim3(gmx, (H * FO) / GBN, TC), 512, 0, stream>>>(g1, 1, 2, N, F0, H * FO, flag);

    AArg a0{};
    for (int i = 0; i < TC; i++) {
      int t = types[i], b = bufs[i];
      a0.hp[i] = hpP(b); a0.sv[i] = svP(b); a0.tv[i] = tvP(b);
      a0.rp[i] = rpb + (size_t)t * (N + 1); a0.col[i] = colb + (size_t)t * E;
      a0.out[i] = xbufP(b);
    }
    aggregate<<<dim3((N + 3) / 4, TC), 256, 0, stream>>>(a0, N, 0);

    GArg g2{};
    for (int i = 0; i < TC; i++) {
      int t = types[i], b = bufs[i];
      g2.A[i] = xbufP(b); g2.B[i] = gw[t][1]; g2.C[i] = hpP(b);
      g2.sa[i] = gasrc[t][1]; g2.sb[i] = gatrg[t][1]; g2.sv[i] = svP(b); g2.tv[i] = tvP(b);
    }
    gemm_mfma<<<dim3(gmx, (H * FO) / GBN, TC), 512, 0, stream>>>(g2, 0, 1, N, H * FO, H * FO, flag);

    AArg a1{};
    for (int i = 0; i < TC; i++) {
      int t = types[i], b = bufs[i];
      a1.hp[i] = hpP(b); a1.sv[i] = svP(b); a1.tv[i] = tvP(b);
      a1.rp[i] = rpb + (size_t)t * (N + 1); a1.col[i] = colb + (size_t)t * E;
      a1.out[i] = ta + (size_t)t * FO;
    }
    aggregate<<<dim3((N + 3) / 4, TC), 256, 0, stream>>>(a1, N, 1);
  }

  final_kernel<<<(N + FN - 1) / FN, 256, 0, stream>>>(ta, favec, aw2, am, fcw, fcb, d_out, N, flag);
}

// Round 12
// 575.627 us; speedup vs baseline: 1.0234x; 1.0155x over previous
//
#include <hip/hip_runtime.h>
#include <hip/hip_bf16.h>

// ---------------------------------------------------------------------------
// HetergatWOConcatFeat — round 13:
//  - gemm_mfma reverted to BN=64/256t (measured best: 93 vs 117us for BN=128)
//    with COALESCED B staging: contiguous 16B loads + swizzled ds_write_b16
//    transpose (was 8x scalar 2B global gathers per slot -> VMEM-latency
//    serialization behind each barrier; MfmaUtil 7%).
//  - g1 (K=128) -> gemm_fullk: full-K A tile staged ONCE in LDS (BM=64,
//    As 16KB + Bs 16KB), internal loop over 8 n-panels staging only B.
//    Kills the 8x A-panel re-read (FETCH 169MB for 20MB input).
//  - aggregate / final / favec2 / CSR / batching unchanged from round 12.
// ---------------------------------------------------------------------------

typedef __hip_bfloat16 bf16;
typedef __attribute__((ext_vector_type(8))) short short8;
typedef __attribute__((ext_vector_type(4))) float f32x4;

__device__ __forceinline__ float bf2f(bf16 v) { return __bfloat162float(v); }
__device__ __forceinline__ float ldin(const void* p, long i, int f32) {
  return f32 ? ((const float*)p)[i] : bf2f(((const bf16*)p)[i]);
}
__device__ __forceinline__ short f2bfbits(float f) {
  bf16 h = __float2bfloat16(f);
  return *reinterpret_cast<short*>(&h);
}
__device__ __forceinline__ float bfbits2f(short b) {
  unsigned u = ((unsigned)(unsigned short)b) << 16;
  return __uint_as_float(u);
}

struct GArg {
  const void* A[2];
  const void* B[2];
  bf16* C[2];
  const void* sa[2];
  const void* sb[2];
  float* sv[2];
  float* tv[2];
};

struct AArg {
  const bf16* hp[2];
  const float* sv[2];
  const float* tv[2];
  const int* rp[2];
  const int* col[2];
  void* out[2];
};

// Detect input dtype: read first 2048 elements of hemb0 as bf16. If the data
// is really f32, the mantissa halves decode to huge/NaN values.
__global__ __launch_bounds__(64) void detect_kernel(const void* __restrict__ x,
                                                    int* __restrict__ flag) {
  int tid = threadIdx.x;
  float m = 0.f;
  for (int i = tid; i < 2048; i += 64) {
    float v = fabsf(bf2f(((const bf16*)x)[i]));
    if (!(v <= 1e3f)) v = 1e9f;  // NaN/Inf/big -> force detect
    m = fmaxf(m, v);
  }
#pragma unroll
  for (int off = 32; off; off >>= 1) m = fmaxf(m, __shfl_xor(m, off));
  if (tid == 0) flag[0] = (m > 1e3f) ? 1 : 0;
}

// ---------------------------------------------------------------------------
// MFMA GEMM (K-step form): C[M][Nc] bf16 = A[M][K] @ B[K][Nc], fp32 accum.
// amode: 0 = A ws bf16; 1 = A input (dtype by flag).
// bmode: 0 = B row-major input; 1 = B head-blocked [H][K][64] input;
//        2 = B row-major WS bf16.
// Tile BM=128, BN=64, BK=64; 256 threads / 4 waves; acc[2][4].
// B staged via contiguous 16B row loads + swizzled ds_write_b16 transpose.
// Fused st when sv[z] != null (Nc=512, head = blockIdx.y).
// ---------------------------------------------------------------------------
#define GBM 128
#define GBN 64
#define GBK 64

__device__ __forceinline__ int swz(int row, int kbyte) {
  return row * 128 + (kbyte ^ ((row & 7) << 4));
}

__global__ __launch_bounds__(256) void gemm_mfma(GArg g, int amode, int bmode,
                                                 int M, int K, int Nc,
                                                 const int* __restrict__ flag) {
  __shared__ bf16 As[GBM * GBK];
  __shared__ bf16 Bs[GBN * GBK];
  const int z = blockIdx.z;
  const void* __restrict__ A = g.A[z];
  const void* __restrict__ B = g.B[z];
  bf16* __restrict__ C = g.C[z];
  const void* stasrc = g.sa[z];
  const void* statrg = g.sb[z];
  float* svp = g.sv[z];
  float* tvp = g.tv[z];
  const int f32 = flag[0];
  const int af32 = (amode == 1) ? f32 : 0;
  const int bf32 = (bmode == 2) ? 0 : f32;
  const int m0 = blockIdx.x * GBM;
  const int n0 = blockIdx.y * GBN;
  const int tid = threadIdx.x;
  const int lane = tid & 63;
  const int wrow = (tid >> 6) * 32;

  f32x4 acc[2][4];
#pragma unroll
  for (int m = 0; m < 2; m++)
#pragma unroll
    for (int n = 0; n < 4; n++)
#pragma unroll
      for (int r = 0; r < 4; r++) acc[m][n][r] = 0.f;

  for (int kt = 0; kt < K; kt += GBK) {
    // ---- stage A: 128 rows x 64 k, 1024 16B slots, 4/thread ----
#pragma unroll
    for (int j = 0; j < 4; j++) {
      int idx = tid + j * 256;       // 0..1023
      int row = idx >> 3;            // 0..127
      int ks = idx & 7;              // 16B slot within row
      int gm = m0 + row;
      short8 v;
#pragma unroll
      for (int e = 0; e < 8; e++) v[e] = 0;
      if (gm < M) {
        long base = (long)gm * K + kt + ks * 8;
        if (!af32) {
          v = *(const short8*)((const bf16*)A + base);
        } else {
          const float* Af = (const float*)A + base;
          float4 x0 = *(const float4*)Af;
          float4 x1 = *(const float4*)(Af + 4);
          v[0] = f2bfbits(x0.x); v[1] = f2bfbits(x0.y);
          v[2] = f2bfbits(x0.z); v[3] = f2bfbits(x0.w);
          v[4] = f2bfbits(x1.x); v[5] = f2bfbits(x1.y);
          v[6] = f2bfbits(x1.z); v[7] = f2bfbits(x1.w);
        }
      }
      *(short8*)((char*)As + swz(row, ks * 16)) = v;
    }
    // ---- stage B coalesced: 512 slots (k 0..63 x colblk 0..7), 2/thread.
    //      Load 16B contiguous row segment, transpose via 8 b16 LDS writes.
#pragma unroll
    for (int j = 0; j < 2; j++) {
      int idx = tid + j * 256;       // 0..511
      int k = idx >> 3;              // 0..63
      int colblk = idx & 7;          // 8 cols each
      long base;
      if (bmode == 1) base = ((long)blockIdx.y * K + kt + k) * 64 + colblk * 8;
      else base = (long)(kt + k) * Nc + n0 + colblk * 8;
      short8 v;
      if (bf32) {
        const float* Bf = (const float*)B + base;
        float4 x0 = *(const float4*)Bf;
        float4 x1 = *(const float4*)(Bf + 4);
        v[0] = f2bfbits(x0.x); v[1] = f2bfbits(x0.y);
        v[2] = f2bfbits(x0.z); v[3] = f2bfbits(x0.w);
        v[4] = f2bfbits(x1.x); v[5] = f2bfbits(x1.y);
        v[6] = f2bfbits(x1.z); v[7] = f2bfbits(x1.w);
      } else {
        v = *(const short8*)((const bf16*)B + base);
      }
#pragma unroll
      for (int e = 0; e < 8; e++)
        *(short*)((char*)Bs + swz(colblk * 8 + e, k * 2)) = v[e];
    }
    __syncthreads();
    // ---- compute: 2 k-halves of 32, per wave 2x4 fragments ----
#pragma unroll
    for (int kh = 0; kh < 2; kh++) {
      int klane = kh * 64 + ((lane >> 4) << 4);
      short8 af[2], bfr[4];
#pragma unroll
      for (int m = 0; m < 2; m++) {
        int row = wrow + m * 16 + (lane & 15);
        af[m] = *(const short8*)((const char*)As + swz(row, klane));
      }
#pragma unroll
      for (int n = 0; n < 4; n++) {
        int col = n * 16 + (lane & 15);
        bfr[n] = *(const short8*)((const char*)Bs + swz(col, klane));
      }
#pragma unroll
      for (int m = 0; m < 2; m++)
#pragma unroll
        for (int n = 0; n < 4; n++)
          acc[m][n] = __builtin_amdgcn_mfma_f32_16x16x32_bf16(af[m], bfr[n], acc[m][n], 0, 0, 0);
    }
    __syncthreads();
  }
  // ---- fused st: s/t from fp32 acc (head h = blockIdx.y) ----
  if (svp) {
    const int h = blockIdx.y;
    const int cl = lane & 15;
    float av[4], bv[4];
#pragma unroll
    for (int n = 0; n < 4; n++) {
      av[n] = ldin(stasrc, h * 64 + n * 16 + cl, f32);
      bv[n] = ldin(statrg, h * 64 + n * 16 + cl, f32);
    }
#pragma unroll
    for (int m = 0; m < 2; m++) {
#pragma unroll
      for (int r = 0; r < 4; r++) {
        float s = 0.f, t = 0.f;
#pragma unroll
        for (int n = 0; n < 4; n++) {
          s += acc[m][n][r] * av[n];
          t += acc[m][n][r] * bv[n];
        }
#pragma unroll
        for (int off = 1; off <= 8; off <<= 1) {
          s += __shfl_xor(s, off);
          t += __shfl_xor(t, off);
        }
        int row = m0 + wrow + m * 16 + ((lane >> 4) << 2) + r;
        if (cl == 0 && row < M) {
          svp[(long)row * 8 + h] = s;
          tvp[(long)row * 8 + h] = t;
        }
      }
    }
  }
  // ---- C write ----
#pragma unroll
  for (int m = 0; m < 2; m++) {
#pragma unroll
    for (int r = 0; r < 4; r++) {
      int row = m0 + wrow + m * 16 + ((lane >> 4) << 2) + r;
      if (row < M) {
#pragma unroll
        for (int n = 0; n < 4; n++) {
          int col = n0 + n * 16 + (lane & 15);
          C[(long)row * Nc + col] = __float2bfloat16(acc[m][n][r]);
        }
      }
    }
  }
}

// ---------------------------------------------------------------------------
// gemm_fullk: specialized hp-layer-0 GEMM. K=128 (full in LDS), Nc=512.
// C = A[M][128] @ B[128][512], A input (dtype by flag), B ws bf16 row-major.
// BM=64, 256 threads / 4 waves (wave w: rows w*16..w*16+15, acc[4]).
// A staged ONCE (16KB); loop over 8 n-panels (head = p), staging Bs 16KB
// each (coalesced 16B loads + swizzled b16 transpose). Fused st per panel.
// LDS rows are 256B (K=128): swz256.
// ---------------------------------------------------------------------------
#define FKBM 64

__device__ __forceinline__ int swz256(int row, int kbyte) {
  return row * 256 + (kbyte ^ ((row & 7) << 4));
}

__global__ __launch_bounds__(256) void gemm_fullk(GArg g, int M,
                                                  const int* __restrict__ flag) {
  __shared__ bf16 As[FKBM * 128];   // 16KB
  __shared__ bf16 Bs[64 * 128];     // 16KB per panel
  const int z = blockIdx.z;
  const void* __restrict__ A = g.A[z];
  const bf16* __restrict__ B = (const bf16*)g.B[z];
  bf16* __restrict__ C = g.C[z];
  const void* stasrc = g.sa[z];
  const void* statrg = g.sb[z];
  float* svp = g.sv[z];
  float* tvp = g.tv[z];
  const int f32 = flag[0];
  const int m0 = blockIdx.x * FKBM;
  const int tid = threadIdx.x;
  const int lane = tid & 63;
  const int wrow = (tid >> 6) * 16;

  // ---- stage A once: 64 rows x 128 k = 1024 16B slots, 4/thread ----
#pragma unroll
  for (int j = 0; j < 4; j++) {
    int idx = tid + j * 256;       // 0..1023
    int row = idx >> 4;            // 0..63
    int ks = idx & 15;             // 16 slots per 256B row
    int gm = m0 + row;
    short8 v;
#pragma unroll
    for (int e = 0; e < 8; e++) v[e] = 0;
    if (gm < M) {
      long base = (long)gm * 128 + ks * 8;
      if (!f32) {
        v = *(const short8*)((const bf16*)A + base);
      } else {
        const float* Af = (const float*)A + base;
        float4 x0 = *(const float4*)Af;
        float4 x1 = *(const float4*)(Af + 4);
        v[0] = f2bfbits(x0.x); v[1] = f2bfbits(x0.y);
        v[2] = f2bfbits(x0.z); v[3] = f2bfbits(x0.w);
        v[4] = f2bfbits(x1.x); v[5] = f2bfbits(x1.y);
        v[6] = f2bfbits(x1.z); v[7] = f2bfbits(x1.w);
      }
    }
    *(short8*)((char*)As + swz256(row, ks * 16)) = v;
  }

  for (int p = 0; p < 8; p++) {
    // ---- stage Bs for panel p: 128 k x 8 colblk = 1024 slots, 4/thread ----
#pragma unroll
    for (int j = 0; j < 4; j++) {
      int idx = tid + j * 256;     // 0..1023
      int k = idx >> 3;            // 0..127
      int colblk = idx & 7;
      short8 v = *(const short8*)(B + (long)k * 512 + p * 64 + colblk * 8);
#pragma unroll
      for (int e = 0; e < 8; e++)
        *(short*)((char*)Bs + swz256(colblk * 8 + e, k * 2)) = v[e];
    }
    __syncthreads();
    // ---- compute panel: 4 k-blocks of 32, acc[4] ----
    f32x4 acc[4];
#pragma unroll
    for (int n = 0; n < 4; n++)
#pragma unroll
      for (int r = 0; r < 4; r++) acc[n][r] = 0.f;
#pragma unroll
    for (int kb = 0; kb < 4; kb++) {
      int klane = kb * 64 + ((lane >> 4) << 4);
      short8 af = *(const short8*)((const char*)As + swz256(wrow + (lane & 15), klane));
      short8 bfr[4];
#pragma unroll
      for (int n = 0; n < 4; n++)
        bfr[n] = *(const short8*)((const char*)Bs + swz256(n * 16 + (lane & 15), klane));
#pragma unroll
      for (int n = 0; n < 4; n++)
        acc[n] = __builtin_amdgcn_mfma_f32_16x16x32_bf16(af, bfr[n], acc[n], 0, 0, 0);
    }
    // ---- fused st for head p ----
    {
      const int cl = lane & 15;
      float av[4], bv[4];
#pragma unroll
      for (int n = 0; n < 4; n++) {
        av[n] = ldin(stasrc, p * 64 + n * 16 + cl, f32);
        bv[n] = ldin(statrg, p * 64 + n * 16 + cl, f32);
      }
#pragma unroll
      for (int r = 0; r < 4; r++) {
        float s = 0.f, t = 0.f;
#pragma unroll
        for (int n = 0; n < 4; n++) {
          s += acc[n][r] * av[n];
          t += acc[n][r] * bv[n];
        }
#pragma unroll
        for (int off = 1; off <= 8; off <<= 1) {
          s += __shfl_xor(s, off);
          t += __shfl_xor(t, off);
        }
        int row = m0 + wrow + ((lane >> 4) << 2) + r;
        if (cl == 0 && row < M) {
          svp[(long)row * 8 + p] = s;
          tvp[(long)row * 8 + p] = t;
        }
      }
    }
    // ---- C write for panel p ----
#pragma unroll
    for (int r = 0; r < 4; r++) {
      int row = m0 + wrow + ((lane >> 4) << 2) + r;
      if (row < M) {
#pragma unroll
        for (int n = 0; n < 4; n++) {
          int col = p * 64 + n * 16 + (lane & 15);
          C[(long)row * 512 + col] = __float2bfloat16(acc[n][r]);
        }
      }
    }
    __syncthreads();  // all waves done with Bs before next panel overwrites
  }
}

// ---- CSR build (both graphs in one pass; deg/fil [2N], rp [2(N+1)]) ----
__global__ void hist2_kernel(const int* __restrict__ trg0, const int* __restrict__ trg1,
                             int* __restrict__ deg, int E, int N) {
  int e = blockIdx.x * 256 + threadIdx.x;
  if (e < E) atomicAdd(&deg[trg0[e]], 1);
  else if (e < 2 * E) atomicAdd(&deg[N + trg1[e - E]], 1);
}

__global__ __launch_bounds__(1024) void scan_kernel(const int* __restrict__ degb,
                                                    int* __restrict__ rpb,
                                                    int* __restrict__ filb, int N) {
  const int* deg = degb + (long)blockIdx.x * N;
  int* row_ptr = rpb + (long)blockIdx.x * (N + 1);
  int* fil = filb + (long)blockIdx.x * N;
  __shared__ int sums[1024];
  int tid = threadIdx.x;
  int chunk = (N + 1023) >> 10;
  int start = tid * chunk;
  int end = start + chunk;
  if (start > N) start = N;
  if (end > N) end = N;
  int s = 0;
  for (int i = start; i < end; i++) s += deg[i];
  sums[tid] = s;
  __syncthreads();
  for (int off = 1; off < 1024; off <<= 1) {
    int add = (tid >= off) ? sums[tid - off] : 0;
    __syncthreads();
    sums[tid] += add;
    __syncthreads();
  }
  int run = (tid > 0) ? sums[tid - 1] : 0;
  for (int i = start; i < end; i++) {
    row_ptr[i] = run;
    fil[i] = run;
    run += deg[i];
  }
  if (tid == 0) row_ptr[N] = sums[1023];
}

__global__ void fill2_kernel(const int* __restrict__ src0, const int* __restrict__ trg0,
                             const int* __restrict__ src1, const int* __restrict__ trg1,
                             int* __restrict__ filb, int* __restrict__ colb, int E, int N) {
  int e = blockIdx.x * 256 + threadIdx.x;
  if (e < E) {
    int t = trg0[e];
    int pos = atomicAdd(&filb[t], 1);
    colb[pos] = src0[e];
  } else if (e < 2 * E) {
    int ee = e - E;
    int t = trg1[ee];
    int pos = atomicAdd(&filb[N + t], 1);
    colb[E + pos] = src1[ee];
  }
}

// ---------------------------------------------------------------------------
// GAT aggregation, fused single pass: out = (Σ_e ex_e · hp[src_e]) / (Σ_e ex_e).
// ONE wave per node (4 nodes per block). Lane c owns bytes [c*16,c*16+16) of
// the 1KB row (head h = c>>3). Edge srcs staged one-per-lane + __shfl
// broadcast; double-buffered 4-edge pipeline. blockIdx.y = type slot.
// ---------------------------------------------------------------------------
__device__ __forceinline__ float exleaky(float v) {
  v = v > 0.f ? v : 0.2f * v;
  return __expf(v);
}

__global__ __launch_bounds__(256) void aggregate(AArg aa, int N, int mode) {
  const int ty = blockIdx.y;
  const bf16* __restrict__ hpb = aa.hp[ty];
  const float* __restrict__ svb = aa.sv[ty];
  const float* __restrict__ tvb = aa.tv[ty];
  const int* __restrict__ rp = aa.rp[ty];
  const int* __restrict__ colv = aa.col[ty];
  void* __restrict__ outp = aa.out[ty];
  const int wid = threadIdx.x >> 6;
  const int lane = threadIdx.x & 63;
  const int n = blockIdx.x * 4 + wid;
  if (n >= N) return;
  const int start = rp[n];
  const int deg = rp[n + 1] - start;
  const int h = lane >> 3;
  const float tvh = tvb[(long)n * 8 + h];
  const bf16* __restrict__ hpc = hpb + lane * 8;

  float acc[8] = {0.f, 0.f, 0.f, 0.f, 0.f, 0.f, 0.f, 0.f};
  float den = 1e-16f;

#define AG_LOAD(EB, V0, V1, V2, V3, Q0, Q1, Q2, Q3)                 \
  {                                                                 \
    int t0 = __shfl(mysrc, (EB) + 0), t1 = __shfl(mysrc, (EB) + 1); \
    int t2 = __shfl(mysrc, (EB) + 2), t3 = __shfl(mysrc, (EB) + 3); \
    V0 = *(const short8*)(hpc + (long)t0 * 512);                    \
    V1 = *(const short8*)(hpc + (long)t1 * 512);                    \
    V2 = *(const short8*)(hpc + (long)t2 * 512);                    \
    V3 = *(const short8*)(hpc + (long)t3 * 512);                    \
    Q0 = svb[(long)t0 * 8 + h];                                     \
    Q1 = svb[(long)t1 * 8 + h];                                     \
    Q2 = svb[(long)t2 * 8 + h];                                     \
    Q3 = svb[(long)t3 * 8 + h];                                     \
  }
#define AG_ACC(V0, V1, V2, V3, Q0, Q1, Q2, Q3)                      \
  {                                                                 \
    float a0 = exleaky(Q0 + tvh), a1 = exleaky(Q1 + tvh);           \
    float a2 = exleaky(Q2 + tvh), a3 = exleaky(Q3 + tvh);           \
    den += a0 + a1 + a2 + a3;                                       \
    _Pragma("unroll")                                               \
    for (int j = 0; j < 8; j++)                                     \
      acc[j] += a0 * bfbits2f(V0[j]) + a1 * bfbits2f(V1[j]) +       \
                a2 * bfbits2f(V2[j]) + a3 * bfbits2f(V3[j]);        \
  }

  for (int base = 0; base < deg; base += 64) {
    int cnt = deg - base;
    if (cnt > 64) cnt = 64;
    int mysrc = (lane < cnt) ? colv[start + base + lane] : 0;
    int nfull = cnt & ~3;
    if (nfull) {
      short8 v0, v1, v2, v3;
      float q0, q1, q2, q3;
      AG_LOAD(0, v0, v1, v2, v3, q0, q1, q2, q3);
      for (int e = 4; e < nfull; e += 4) {
        short8 w0 = v0, w1 = v1, w2 = v2, w3 = v3;
        float p0 = q0, p1 = q1, p2 = q2, p3 = q3;
        AG_LOAD(e, v0, v1, v2, v3, q0, q1, q2, q3);
        AG_ACC(w0, w1, w2, w3, p0, p1, p2, p3);
      }
      AG_ACC(v0, v1, v2, v3, q0, q1, q2, q3);
    }
    for (int e = nfull; e < cnt; e++) {
      int s0 = __shfl(mysrc, e);
      short8 v = *(const short8*)(hpc + (long)s0 * 512);
      float a = exleaky(svb[(long)s0 * 8 + h] + tvh);
      den += a;
#pragma unroll
      for (int j = 0; j < 8; j++) acc[j] += a * bfbits2f(v[j]);
    }
  }

  const float dinv = 1.f / den;
  if (mode == 0) {
    short8 o8;
#pragma unroll
    for (int j = 0; j < 8; j++) {
      float s = acc[j] * dinv;
      float ev = s > 0.f ? s : expm1f(s);
      o8[j] = f2bfbits(ev);
    }
    *(short8*)((bf16*)outp + (long)n * 512 + lane * 8) = o8;
  } else {
    float r[8];
#pragma unroll
    for (int j = 0; j < 8; j++) r[j] = acc[j] * dinv;
#pragma unroll
    for (int m = 8; m <= 32; m <<= 1)
#pragma unroll
      for (int j = 0; j < 8; j++) r[j] += __shfl_xor(r[j], m);
    if (lane < 8) {
      float* o = (float*)outp + (long)n * 128 + lane * 8;
#pragma unroll
      for (int j = 0; j < 8; j++) o[j] = r[j] * 0.125f;
    }
  }
}

// favec[o] = (hemb1[0,:] @ W1) @ aw1[:,o]  — one 256-thread block.
__global__ __launch_bounds__(256) void favec2_kernel(const void* __restrict__ hemb1,
                                                     const void* __restrict__ W1,
                                                     const void* __restrict__ aw1,
                                                     float* __restrict__ favec,
                                                     const int* __restrict__ flag) {
  const int f32 = flag[0];
  __shared__ float s_h[128];
  __shared__ float s_r[256];
  __shared__ float part[4][64];
  const int tid = threadIdx.x;
  if (tid < 128) s_h[tid] = ldin(hemb1, tid, f32);
  __syncthreads();
  float r = 0.f;
  for (int i = 0; i < 128; i++) r += s_h[i] * ldin(W1, (long)i * 256 + tid, f32);
  s_r[tid] = r;
  __syncthreads();
  const int o = tid & 63;
  const int wv = tid >> 6;
  float acc = 0.f;
#pragma unroll
  for (int kk = 0; kk < 64; kk++) {
    int k = wv * 64 + kk;
    acc += s_r[k] * ldin(aw1, (long)k * 64 + o, f32);
  }
  part[wv][o] = acc;
  __syncthreads();
  if (tid < 64) favec[o] = part[0][o] + part[1][o] + part[2][o] + part[3][o];
}

// ---------------------------------------------------------------------------
// Semantic attention + FC + log_softmax. 16 nodes per 256-thread block.
// ---------------------------------------------------------------------------
#define FN 16
__global__ __launch_bounds__(256) void final_kernel(const float* __restrict__ ta,
                                                    const float* __restrict__ favec,
                                                    const void* __restrict__ aw2,
                                                    const void* __restrict__ am,
                                                    const void* __restrict__ fcw,
                                                    const void* __restrict__ fcb,
                                                    void* __restrict__ out, int N,
                                                    const int* __restrict__ flag) {
  const int f32 = flag[0];
  __shared__ float s_w[64 * 64];
  __shared__ float s_fc[384];
  __shared__ float s_misc[130];
  __shared__ float s_ta[FN * 128];
  const int tid = threadIdx.x;
  const int n0 = blockIdx.x * FN;
  for (int i = tid; i < 4096; i += 256) s_w[i] = ldin(aw2, i, f32);
  for (int i = tid; i < 384; i += 256) s_fc[i] = ldin(fcw, i, f32);
  if (tid < 64) s_misc[tid] = favec[tid];
  else if (tid < 128) s_misc[tid] = ldin(am, tid - 64, f32);
  else if (tid < 130) s_misc[tid] = ldin(fcb, tid - 128, f32);
  for (int idx = tid; idx < FN * 128; idx += 256) {
    int ni = idx >> 7;
    int j = idx & 127;
    int k = j >> 1, r = j & 1;
    int n = n0 + ni;
    s_ta[idx] = (n < N) ? ta[(long)n * 128 + r * 64 + k] : 0.f;
  }
  __syncthreads();
  const int o = tid & 63;
  const int wv = tid >> 6;
#pragma unroll
  for (int ni4 = 0; ni4 < 4; ni4++) {
    const int ni = wv * 4 + ni4;
    const int n = n0 + ni;
    if (n >= N) continue;
    const float* tb = &s_ta[ni * 128];
    float acc0 = s_misc[o], acc1 = acc0;
#pragma unroll 8
    for (int k = 0; k < 64; k++) {
      float2 t2 = *(const float2*)(tb + k * 2);
      float w = s_w[k * 64 + o];
      acc0 += t2.x * w;
      acc1 += t2.y * w;
    }
    float ta0 = tb[o * 2];
    float ta1 = tb[o * 2 + 1];
    float amv = s_misc[64 + o];
    float p0 = tanhf(acc0) * amv;
    float p1 = tanhf(acc1) * amv;
#pragma unroll
    for (int off = 32; off > 0; off >>= 1) {
      p0 += __shfl_xor(p0, off);
      p1 += __shfl_xor(p1, off);
    }
    float mx = fmaxf(p0, p1);
    float e0 = __expf(p0 - mx), e1 = __expf(p1 - mx);
    float b0 = e0 / (e0 + e1), b1 = e1 / (e0 + e1);
    float fus = b0 * ta0 + b1 * ta1;
    float l0 = ta0 * s_fc[o * 2 + 0] + ta1 * s_fc[(64 + o) * 2 + 0] + fus * s_fc[(128 + o) * 2 + 0];
    float l1 = ta0 * s_fc[o * 2 + 1] + ta1 * s_fc[(64 + o) * 2 + 1] + fus * s_fc[(128 + o) * 2 + 1];
#pragma unroll
    for (int off = 32; off > 0; off >>= 1) {
      l0 += __shfl_xor(l0, off);
      l1 += __shfl_xor(l1, off);
    }
    if (o == 0) {
      l0 += s_misc[128];
      l1 += s_misc[129];
      float m2 = fmaxf(l0, l1);
      float lse = m2 + logf(__expf(l0 - m2) + __expf(l1 - m2));
      if (f32) {
        ((float*)out)[n * 2 + 0] = l0 - lse;
        ((float*)out)[n * 2 + 1] = l1 - lse;
      } else {
        ((bf16*)out)[n * 2 + 0] = __float2bfloat16(l0 - lse);
        ((bf16*)out)[n * 2 + 1] = __float2bfloat16(l1 - lse);
      }
    }
  }
}

extern "C" void kernel_launch(void* const* d_in, const int* in_sizes, int n_in,
                              void* d_out, int out_size, void* d_ws, size_t ws_size,
                              hipStream_t stream) {
  constexpr int N = 20000, E = 320000, H = 8, F0 = 128, FU = 256, FO = 64;
  const void* hemb[2] = {d_in[0], d_in[1]};
  const void* W[2] = {d_in[2], d_in[3]};
  const void* gw[2][2] = {{d_in[4], d_in[7]}, {d_in[10], d_in[13]}};
  const void* gasrc[2][2] = {{d_in[5], d_in[8]}, {d_in[11], d_in[14]}};
  const void* gatrg[2][2] = {{d_in[6], d_in[9]}, {d_in[12], d_in[15]}};
  const void* aw1 = d_in[16];
  const void* aw2 = d_in[17];
  const void* am = d_in[18];
  const void* fcw = d_in[19];
  const void* fcb = d_in[20];
  const int* edge[2] = {(const int*)d_in[21], (const int*)d_in[22]};

  const size_t szWg = (size_t)F0 * 512 * 2;
  const size_t szHp = (size_t)N * 512 * 2;
  const size_t szSv = (size_t)N * 8 * 4;
  size_t need = 0;
  auto addsz = [&](size_t b) { need += (b + 255) & ~(size_t)255; };
  addsz(4);
  addsz(szWg * 2);
  addsz(szHp * 2); addsz(szHp * 2);
  addsz(szSv * 2); addsz(szSv * 2);
  addsz((size_t)N * 128 * 4); addsz(256);
  addsz((size_t)2 * N * 4); addsz((size_t)2 * (N + 1) * 4);
  addsz((size_t)2 * N * 4); addsz((size_t)2 * E * 4);
  const bool batched = (ws_size >= need + 4096);
  const int TB = batched ? 2 : 1;

  char* p = (char*)d_ws;
  auto alloc = [&](size_t bytes) -> void* {
    void* r = (void*)p;
    p += (bytes + 255) & ~(size_t)255;
    return r;
  };
  int* flag = (int*)alloc(4);
  bf16* wg = (bf16*)alloc(szWg * 2);
  bf16* hp = (bf16*)alloc(szHp * TB);
  bf16* xbuf = (bf16*)alloc(szHp * TB);
  float* sv = (float*)alloc(szSv * TB);
  float* tv = (float*)alloc(szSv * TB);
  float* ta = (float*)alloc((size_t)N * 128 * 4);
  float* favec = (float*)alloc(256);
  int* degb = (int*)alloc((size_t)2 * N * 4);
  int* rpb = (int*)alloc((size_t)2 * (N + 1) * 4);
  int* filb = (int*)alloc((size_t)2 * N * 4);
  int* colb = (int*)alloc((size_t)2 * E * 4);

  detect_kernel<<<1, 64, 0, stream>>>(hemb[0], flag);

  // CSR build for both graphs in one pass
  hipMemsetAsync(degb, 0, (size_t)2 * N * 4, stream);
  hist2_kernel<<<(2 * E + 255) / 256, 256, 0, stream>>>(edge[0] + E, edge[1] + E, degb, E, N);
  scan_kernel<<<2, 1024, 0, stream>>>(degb, rpb, filb, N);
  fill2_kernel<<<(2 * E + 255) / 256, 256, 0, stream>>>(edge[0], edge[0] + E,
                                                        edge[1], edge[1] + E, filb, colb, E, N);

  // favec from inputs directly
  favec2_kernel<<<1, 256, 0, stream>>>(hemb[1], W[1], aw1, favec, flag);

  // Wg[t] = W[t] @ gw[t][0] : [128][512] bf16 ws (both types in one launch)
  {
    GArg gW{};
    for (int i = 0; i < 2; i++) {
      gW.A[i] = W[i]; gW.B[i] = gw[i][0]; gW.C[i] = wg + (size_t)i * F0 * 512;
      gW.sa[i] = nullptr; gW.sb[i] = nullptr; gW.sv[i] = nullptr; gW.tv[i] = nullptr;
    }
    gemm_mfma<<<dim3(1, (H * FO) / GBN, 2), 256, 0, stream>>>(gW, 1, 1, F0, FU, H * FO, flag);
  }

  const int gmx = (N + GBM - 1) / GBM;    // 157
  const int gfk = (N + FKBM - 1) / FKBM;  // 313
  const int npass = batched ? 1 : 2;
  const int TC = batched ? 2 : 1;

  auto hpP = [&](int b) { return hp + (size_t)b * N * 512; };
  auto xbufP = [&](int b) { return xbuf + (size_t)b * N * 512; };
  auto svP = [&](int b) { return sv + (size_t)b * N * 8; };
  auto tvP = [&](int b) { return tv + (size_t)b * N * 8; };

  for (int pass = 0; pass < npass; pass++) {
    int types[2] = {batched ? 0 : pass, batched ? 1 : pass};
    int bufs[2] = {0, batched ? 1 : 0};

    // hp layer 0: A = hemb (input, K=128), B = Wg (ws bf16) — full-K kernel
    GArg g1{};
    for (int i = 0; i < TC; i++) {
      int t = types[i], b = bufs[i];
      g1.A[i] = hemb[t]; g1.B[i] = wg + (size_t)t * F0 * 512; g1.C[i] = hpP(b);
      g1.sa[i] = gasrc[t][0]; g1.sb[i] = gatrg[t][0]; g1.sv[i] = svP(b); g1.tv[i] = tvP(b);
    }
    gemm_fullk<<<dim3(gfk, 1, TC), 256, 0, stream>>>(g1, N, flag);

    AArg a0{};
    for (int i = 0; i < TC; i++) {
      int t = types[i], b = bufs[i];
      a0.hp[i] = hpP(b); a0.sv[i] = svP(b); a0.tv[i] = tvP(b);
      a0.rp[i] = rpb + (size_t)t * (N + 1); a0.col[i] = colb + (size_t)t * E;
      a0.out[i] = xbufP(b);
    }
    aggregate<<<dim3((N + 3) / 4, TC), 256, 0, stream>>>(a0, N, 0);

    GArg g2{};
    for (int i = 0; i < TC; i++) {
      int t = types[i], b = bufs[i];
      g2.A[i] = xbufP(b); g2.B[i] = gw[t][1]; g2.C[i] = hpP(b);
      g2.sa[i] = gasrc[t][1]; g2.sb[i] = gatrg[t][1]; g2.sv[i] = svP(b); g2.tv[i] = tvP(b);
    }
    gemm_mfma<<<dim3(gmx, (H * FO) / GBN, TC), 256, 0, stream>>>(g2, 0, 1, N, H * FO, H * FO, flag);

    AArg a1{};
    for (int i = 0; i < TC; i++) {
      int t = types[i], b = bufs[i];
      a1.hp[i] = hpP(b); a1.sv[i] = svP(b); a1.tv[i] = tvP(b);
      a1.rp[i] = rpb + (size_t)t * (N + 1); a1.col[i] = colb + (size_t)t * E;
      a1.out[i] = ta + (size_t)t * FO;
    }
    aggregate<<<dim3((N + 3) / 4, TC), 256, 0, stream>>>(a1, N, 1);
  }

  final_kernel<<<(N + FN - 1) / FN, 256, 0, stream>>>(ta, favec, aw2, am, fcw, fcb, d_out, N, flag);
}

// Round 13
// 558.011 us; speedup vs baseline: 1.0557x; 1.0316x over previous
//
#include <hip/hip_runtime.h>
#include <hip/hip_bf16.h>

// ---------------------------------------------------------------------------
// HetergatWOConcatFeat — round 14:
//  - gemm_mfma: XCD-coresidency decode. Grid flattened 1D; (x,y) decoded so
//    all 8 n-blocks sharing an A-panel have equal d%8 -> same XCD -> panel
//    fetched once per XCD (round-13 FETCH=169MB = 8x A re-read because
//    157-apart sharers spread across all 8 XCD L2s; 157 mod 8 = 5).
//  - B staging reverted to round-10 scalar-gather (round-13's b16-scatter
//    transpose added 1.8e7 bank conflicts, 97 vs 93us).
//  - gemm_fullk (g1, A staged once, K=128) kept. 40ms outlier in r13 profile
//    identified as rocprof replay artifact (absent from 575us total).
//  - aggregate / final / favec2 / CSR / batching unchanged.
// ---------------------------------------------------------------------------

typedef __hip_bfloat16 bf16;
typedef __attribute__((ext_vector_type(8))) short short8;
typedef __attribute__((ext_vector_type(4))) float f32x4;

__device__ __forceinline__ float bf2f(bf16 v) { return __bfloat162float(v); }
__device__ __forceinline__ float ldin(const void* p, long i, int f32) {
  return f32 ? ((const float*)p)[i] : bf2f(((const bf16*)p)[i]);
}
__device__ __forceinline__ short f2bfbits(float f) {
  bf16 h = __float2bfloat16(f);
  return *reinterpret_cast<short*>(&h);
}
__device__ __forceinline__ float bfbits2f(short b) {
  unsigned u = ((unsigned)(unsigned short)b) << 16;
  return __uint_as_float(u);
}

struct GArg {
  const void* A[2];
  const void* B[2];
  bf16* C[2];
  const void* sa[2];
  const void* sb[2];
  float* sv[2];
  float* tv[2];
};

struct AArg {
  const bf16* hp[2];
  const float* sv[2];
  const float* tv[2];
  const int* rp[2];
  const int* col[2];
  void* out[2];
};

// Detect input dtype: read first 2048 elements of hemb0 as bf16. If the data
// is really f32, the mantissa halves decode to huge/NaN values.
__global__ __launch_bounds__(64) void detect_kernel(const void* __restrict__ x,
                                                    int* __restrict__ flag) {
  int tid = threadIdx.x;
  float m = 0.f;
  for (int i = tid; i < 2048; i += 64) {
    float v = fabsf(bf2f(((const bf16*)x)[i]));
    if (!(v <= 1e3f)) v = 1e9f;  // NaN/Inf/big -> force detect
    m = fmaxf(m, v);
  }
#pragma unroll
  for (int off = 32; off; off >>= 1) m = fmaxf(m, __shfl_xor(m, off));
  if (tid == 0) flag[0] = (m > 1e3f) ? 1 : 0;
}

// ---------------------------------------------------------------------------
// MFMA GEMM (K-step form): C[M][Nc] bf16 = A[M][K] @ B[K][Nc], fp32 accum.
// amode: 0 = A ws bf16; 1 = A input (dtype by flag).
// bmode: 0 = B row-major input; 1 = B head-blocked [H][K][64] input;
//        2 = B row-major WS bf16.
// Tile BM=128, BN=64, BK=64; 256 threads / 4 waves; acc[2][4]. LDS 24KB.
// GRID IS 1D: gridDim.x = nx*8 (nx m-panels x 8 n-panels). Decode puts all
// 8 sharers of an A-panel at equal d%8 (same XCD under round-robin dispatch)
// -> A panel fetched once per XCD instead of 8x.
// Fused st when sv[z] != null (Nc=512, head = y).
// ---------------------------------------------------------------------------
#define GBM 128
#define GBN 64
#define GBK 64

__device__ __forceinline__ int swz(int row, int kbyte) {
  return row * 128 + (kbyte ^ ((row & 7) << 4));
}

__global__ __launch_bounds__(256) void gemm_mfma(GArg g, int amode, int bmode,
                                                 int M, int K, int Nc,
                                                 const int* __restrict__ flag) {
  __shared__ bf16 As[GBM * GBK];
  __shared__ bf16 Bs[GBN * GBK];
  const int z = blockIdx.z;
  const void* __restrict__ A = g.A[z];
  const void* __restrict__ B = g.B[z];
  bf16* __restrict__ C = g.C[z];
  const void* stasrc = g.sa[z];
  const void* statrg = g.sb[z];
  float* svp = g.sv[z];
  float* tvp = g.tv[z];
  const int f32 = flag[0];
  const int af32 = (amode == 1) ? f32 : 0;
  const int bf32 = (bmode == 2) ? 0 : f32;

  // ---- XCD-coresidency decode: sharers of one A-panel share d%8 ----
  const int nx = gridDim.x >> 3;
  const int d = blockIdx.x;
  const int fullC = (gridDim.x >> 6) << 6;
  int x, y;
  if (d < fullC) {
    x = (d & 7) + ((d >> 6) << 3);
    y = (d >> 3) & 7;
  } else {
    int l = d - fullC;
    int xbase = fullC >> 3;
    int nrem = nx - xbase;
    x = xbase + l % nrem;
    y = l / nrem;
  }
  const int m0 = x * GBM;
  const int n0 = y * GBN;
  const int tid = threadIdx.x;
  const int lane = tid & 63;
  const int wrow = (tid >> 6) * 32;

  f32x4 acc[2][4];
#pragma unroll
  for (int m = 0; m < 2; m++)
#pragma unroll
    for (int n = 0; n < 4; n++)
#pragma unroll
      for (int r = 0; r < 4; r++) acc[m][n][r] = 0.f;

  for (int kt = 0; kt < K; kt += GBK) {
    // ---- stage A: 128 rows x 64 k, 1024 16B slots, 4/thread ----
#pragma unroll
    for (int j = 0; j < 4; j++) {
      int idx = tid + j * 256;       // 0..1023
      int row = idx >> 3;            // 0..127
      int ks = idx & 7;              // 16B slot within row
      int gm = m0 + row;
      short8 v;
#pragma unroll
      for (int e = 0; e < 8; e++) v[e] = 0;
      if (gm < M) {
        long base = (long)gm * K + kt + ks * 8;
        if (!af32) {
          v = *(const short8*)((const bf16*)A + base);
        } else {
          const float* Af = (const float*)A + base;
          float4 x0 = *(const float4*)Af;
          float4 x1 = *(const float4*)(Af + 4);
          v[0] = f2bfbits(x0.x); v[1] = f2bfbits(x0.y);
          v[2] = f2bfbits(x0.z); v[3] = f2bfbits(x0.w);
          v[4] = f2bfbits(x1.x); v[5] = f2bfbits(x1.y);
          v[6] = f2bfbits(x1.z); v[7] = f2bfbits(x1.w);
        }
      }
      *(short8*)((char*)As + swz(row, ks * 16)) = v;
    }
    // ---- stage B transposed (scalar gather, round-10 form): Bs[col][k] ----
    {
      int n = tid & 63;
      int ks0 = tid >> 6;  // 0..3
#pragma unroll
      for (int jj = 0; jj < 2; jj++) {
        int ks = ks0 + jj * 4;     // 0..7
        int k = kt + ks * 8;
        int col = n0 + n;
        long base;
        int cstr;
        if (bmode == 1) { base = ((long)(col >> 6) * K + k) * 64 + (col & 63); cstr = 64; }
        else { base = (long)k * Nc + col; cstr = Nc; }
        short8 v;
        if (bf32) {
          const float* Bf = (const float*)B;
#pragma unroll
          for (int e = 0; e < 8; e++) v[e] = f2bfbits(Bf[base + (long)e * cstr]);
        } else {
          const bf16* Bh = (const bf16*)B;
#pragma unroll
          for (int e = 0; e < 8; e++) v[e] = *(const short*)&Bh[base + (long)e * cstr];
        }
        *(short8*)((char*)Bs + swz(n, ks * 16)) = v;
      }
    }
    __syncthreads();
    // ---- compute: 2 k-halves of 32, per wave 2x4 fragments ----
#pragma unroll
    for (int kh = 0; kh < 2; kh++) {
      int klane = kh * 64 + ((lane >> 4) << 4);
      short8 af[2], bfr[4];
#pragma unroll
      for (int m = 0; m < 2; m++) {
        int row = wrow + m * 16 + (lane & 15);
        af[m] = *(const short8*)((const char*)As + swz(row, klane));
      }
#pragma unroll
      for (int n = 0; n < 4; n++) {
        int col = n * 16 + (lane & 15);
        bfr[n] = *(const short8*)((const char*)Bs + swz(col, klane));
      }
#pragma unroll
      for (int m = 0; m < 2; m++)
#pragma unroll
        for (int n = 0; n < 4; n++)
          acc[m][n] = __builtin_amdgcn_mfma_f32_16x16x32_bf16(af[m], bfr[n], acc[m][n], 0, 0, 0);
    }
    __syncthreads();
  }
  // ---- fused st: s/t from fp32 acc (head h = y) ----
  if (svp) {
    const int h = y;
    const int cl = lane & 15;
    float av[4], bv[4];
#pragma unroll
    for (int n = 0; n < 4; n++) {
      av[n] = ldin(stasrc, h * 64 + n * 16 + cl, f32);
      bv[n] = ldin(statrg, h * 64 + n * 16 + cl, f32);
    }
#pragma unroll
    for (int m = 0; m < 2; m++) {
#pragma unroll
      for (int r = 0; r < 4; r++) {
        float s = 0.f, t = 0.f;
#pragma unroll
        for (int n = 0; n < 4; n++) {
          s += acc[m][n][r] * av[n];
          t += acc[m][n][r] * bv[n];
        }
#pragma unroll
        for (int off = 1; off <= 8; off <<= 1) {
          s += __shfl_xor(s, off);
          t += __shfl_xor(t, off);
        }
        int row = m0 + wrow + m * 16 + ((lane >> 4) << 2) + r;
        if (cl == 0 && row < M) {
          svp[(long)row * 8 + h] = s;
          tvp[(long)row * 8 + h] = t;
        }
      }
    }
  }
  // ---- C write ----
#pragma unroll
  for (int m = 0; m < 2; m++) {
#pragma unroll
    for (int r = 0; r < 4; r++) {
      int row = m0 + wrow + m * 16 + ((lane >> 4) << 2) + r;
      if (row < M) {
#pragma unroll
        for (int n = 0; n < 4; n++) {
          int col = n0 + n * 16 + (lane & 15);
          C[(long)row * Nc + col] = __float2bfloat16(acc[m][n][r]);
        }
      }
    }
  }
}

// ---------------------------------------------------------------------------
// gemm_fullk: specialized hp-layer-0 GEMM. K=128 (full in LDS), Nc=512.
// C = A[M][128] @ B[128][512], A input (dtype by flag), B ws bf16 row-major.
// BM=64, 256 threads / 4 waves. A staged ONCE (16KB); loop over 8 n-panels
// (head = p), staging Bs each. LDS rows are 256B (K=128): swz256.
// ---------------------------------------------------------------------------
#define FKBM 64

__device__ __forceinline__ int swz256(int row, int kbyte) {
  return row * 256 + (kbyte ^ ((row & 7) << 4));
}

__global__ __launch_bounds__(256) void gemm_fullk(GArg g, int M,
                                                  const int* __restrict__ flag) {
  __shared__ bf16 As[FKBM * 128];   // 16KB
  __shared__ bf16 Bs[64 * 128];     // 16KB per panel
  const int z = blockIdx.z;
  const void* __restrict__ A = g.A[z];
  const bf16* __restrict__ B = (const bf16*)g.B[z];
  bf16* __restrict__ C = g.C[z];
  const void* stasrc = g.sa[z];
  const void* statrg = g.sb[z];
  float* svp = g.sv[z];
  float* tvp = g.tv[z];
  const int f32 = flag[0];
  const int m0 = blockIdx.x * FKBM;
  const int tid = threadIdx.x;
  const int lane = tid & 63;
  const int wrow = (tid >> 6) * 16;

  // ---- stage A once: 64 rows x 128 k = 1024 16B slots, 4/thread ----
#pragma unroll
  for (int j = 0; j < 4; j++) {
    int idx = tid + j * 256;       // 0..1023
    int row = idx >> 4;            // 0..63
    int ks = idx & 15;             // 16 slots per 256B row
    int gm = m0 + row;
    short8 v;
#pragma unroll
    for (int e = 0; e < 8; e++) v[e] = 0;
    if (gm < M) {
      long base = (long)gm * 128 + ks * 8;
      if (!f32) {
        v = *(const short8*)((const bf16*)A + base);
      } else {
        const float* Af = (const float*)A + base;
        float4 x0 = *(const float4*)Af;
        float4 x1 = *(const float4*)(Af + 4);
        v[0] = f2bfbits(x0.x); v[1] = f2bfbits(x0.y);
        v[2] = f2bfbits(x0.z); v[3] = f2bfbits(x0.w);
        v[4] = f2bfbits(x1.x); v[5] = f2bfbits(x1.y);
        v[6] = f2bfbits(x1.z); v[7] = f2bfbits(x1.w);
      }
    }
    *(short8*)((char*)As + swz256(row, ks * 16)) = v;
  }

  for (int p = 0; p < 8; p++) {
    // ---- stage Bs for panel p: 128 k x 8 colblk = 1024 slots, 4/thread ----
#pragma unroll
    for (int j = 0; j < 4; j++) {
      int idx = tid + j * 256;     // 0..1023
      int k = idx >> 3;            // 0..127
      int colblk = idx & 7;
      short8 v = *(const short8*)(B + (long)k * 512 + p * 64 + colblk * 8);
#pragma unroll
      for (int e = 0; e < 8; e++)
        *(short*)((char*)Bs + swz256(colblk * 8 + e, k * 2)) = v[e];
    }
    __syncthreads();
    // ---- compute panel: 4 k-blocks of 32, acc[4] ----
    f32x4 acc[4];
#pragma unroll
    for (int n = 0; n < 4; n++)
#pragma unroll
      for (int r = 0; r < 4; r++) acc[n][r] = 0.f;
#pragma unroll
    for (int kb = 0; kb < 4; kb++) {
      int klane = kb * 64 + ((lane >> 4) << 4);
      short8 af = *(const short8*)((const char*)As + swz256(wrow + (lane & 15), klane));
      short8 bfr[4];
#pragma unroll
      for (int n = 0; n < 4; n++)
        bfr[n] = *(const short8*)((const char*)Bs + swz256(n * 16 + (lane & 15), klane));
#pragma unroll
      for (int n = 0; n < 4; n++)
        acc[n] = __builtin_amdgcn_mfma_f32_16x16x32_bf16(af, bfr[n], acc[n], 0, 0, 0);
    }
    // ---- fused st for head p ----
    {
      const int cl = lane & 15;
      float av[4], bv[4];
#pragma unroll
      for (int n = 0; n < 4; n++) {
        av[n] = ldin(stasrc, p * 64 + n * 16 + cl, f32);
        bv[n] = ldin(statrg, p * 64 + n * 16 + cl, f32);
      }
#pragma unroll
      for (int r = 0; r < 4; r++) {
        float s = 0.f, t = 0.f;
#pragma unroll
        for (int n = 0; n < 4; n++) {
          s += acc[n][r] * av[n];
          t += acc[n][r] * bv[n];
        }
#pragma unroll
        for (int off = 1; off <= 8; off <<= 1) {
          s += __shfl_xor(s, off);
          t += __shfl_xor(t, off);
        }
        int row = m0 + wrow + ((lane >> 4) << 2) + r;
        if (cl == 0 && row < M) {
          svp[(long)row * 8 + p] = s;
          tvp[(long)row * 8 + p] = t;
        }
      }
    }
    // ---- C write for panel p ----
#pragma unroll
    for (int r = 0; r < 4; r++) {
      int row = m0 + wrow + ((lane >> 4) << 2) + r;
      if (row < M) {
#pragma unroll
        for (int n = 0; n < 4; n++) {
          int col = p * 64 + n * 16 + (lane & 15);
          C[(long)row * 512 + col] = __float2bfloat16(acc[n][r]);
        }
      }
    }
    __syncthreads();  // all waves done with Bs before next panel overwrites
  }
}

// ---- CSR build (both graphs in one pass; deg/fil [2N], rp [2(N+1)]) ----
__global__ void hist2_kernel(const int* __restrict__ trg0, const int* __restrict__ trg1,
                             int* __restrict__ deg, int E, int N) {
  int e = blockIdx.x * 256 + threadIdx.x;
  if (e < E) atomicAdd(&deg[trg0[e]], 1);
  else if (e < 2 * E) atomicAdd(&deg[N + trg1[e - E]], 1);
}

__global__ __launch_bounds__(1024) void scan_kernel(const int* __restrict__ degb,
                                                    int* __restrict__ rpb,
                                                    int* __restrict__ filb, int N) {
  const int* deg = degb + (long)blockIdx.x * N;
  int* row_ptr = rpb + (long)blockIdx.x * (N + 1);
  int* fil = filb + (long)blockIdx.x * N;
  __shared__ int sums[1024];
  int tid = threadIdx.x;
  int chunk = (N + 1023) >> 10;
  int start = tid * chunk;
  int end = start + chunk;
  if (start > N) start = N;
  if (end > N) end = N;
  int s = 0;
  for (int i = start; i < end; i++) s += deg[i];
  sums[tid] = s;
  __syncthreads();
  for (int off = 1; off < 1024; off <<= 1) {
    int add = (tid >= off) ? sums[tid - off] : 0;
    __syncthreads();
    sums[tid] += add;
    __syncthreads();
  }
  int run = (tid > 0) ? sums[tid - 1] : 0;
  for (int i = start; i < end; i++) {
    row_ptr[i] = run;
    fil[i] = run;
    run += deg[i];
  }
  if (tid == 0) row_ptr[N] = sums[1023];
}

__global__ void fill2_kernel(const int* __restrict__ src0, const int* __restrict__ trg0,
                             const int* __restrict__ src1, const int* __restrict__ trg1,
                             int* __restrict__ filb, int* __restrict__ colb, int E, int N) {
  int e = blockIdx.x * 256 + threadIdx.x;
  if (e < E) {
    int t = trg0[e];
    int pos = atomicAdd(&filb[t], 1);
    colb[pos] = src0[e];
  } else if (e < 2 * E) {
    int ee = e - E;
    int t = trg1[ee];
    int pos = atomicAdd(&filb[N + t], 1);
    colb[E + pos] = src1[ee];
  }
}

// ---------------------------------------------------------------------------
// GAT aggregation, fused single pass: out = (Σ_e ex_e · hp[src_e]) / (Σ_e ex_e).
// ONE wave per node (4 nodes per block). Lane c owns bytes [c*16,c*16+16) of
// the 1KB row (head h = c>>3). Edge srcs staged one-per-lane + __shfl
// broadcast; double-buffered 4-edge pipeline. blockIdx.y = type slot.
// ---------------------------------------------------------------------------
__device__ __forceinline__ float exleaky(float v) {
  v = v > 0.f ? v : 0.2f * v;
  return __expf(v);
}

__global__ __launch_bounds__(256) void aggregate(AArg aa, int N, int mode) {
  const int ty = blockIdx.y;
  const bf16* __restrict__ hpb = aa.hp[ty];
  const float* __restrict__ svb = aa.sv[ty];
  const float* __restrict__ tvb = aa.tv[ty];
  const int* __restrict__ rp = aa.rp[ty];
  const int* __restrict__ colv = aa.col[ty];
  void* __restrict__ outp = aa.out[ty];
  const int wid = threadIdx.x >> 6;
  const int lane = threadIdx.x & 63;
  const int n = blockIdx.x * 4 + wid;
  if (n >= N) return;
  const int start = rp[n];
  const int deg = rp[n + 1] - start;
  const int h = lane >> 3;
  const float tvh = tvb[(long)n * 8 + h];
  const bf16* __restrict__ hpc = hpb + lane * 8;

  float acc[8] = {0.f, 0.f, 0.f, 0.f, 0.f, 0.f, 0.f, 0.f};
  float den = 1e-16f;

#define AG_LOAD(EB, V0, V1, V2, V3, Q0, Q1, Q2, Q3)                 \
  {                                                                 \
    int t0 = __shfl(mysrc, (EB) + 0), t1 = __shfl(mysrc, (EB) + 1); \
    int t2 = __shfl(mysrc, (EB) + 2), t3 = __shfl(mysrc, (EB) + 3); \
    V0 = *(const short8*)(hpc + (long)t0 * 512);                    \
    V1 = *(const short8*)(hpc + (long)t1 * 512);                    \
    V2 = *(const short8*)(hpc + (long)t2 * 512);                    \
    V3 = *(const short8*)(hpc + (long)t3 * 512);                    \
    Q0 = svb[(long)t0 * 8 + h];                                     \
    Q1 = svb[(long)t1 * 8 + h];                                     \
    Q2 = svb[(long)t2 * 8 + h];                                     \
    Q3 = svb[(long)t3 * 8 + h];                                     \
  }
#define AG_ACC(V0, V1, V2, V3, Q0, Q1, Q2, Q3)                      \
  {                                                                 \
    float a0 = exleaky(Q0 + tvh), a1 = exleaky(Q1 + tvh);           \
    float a2 = exleaky(Q2 + tvh), a3 = exleaky(Q3 + tvh);           \
    den += a0 + a1 + a2 + a3;                                       \
    _Pragma("unroll")                                               \
    for (int j = 0; j < 8; j++)                                     \
      acc[j] += a0 * bfbits2f(V0[j]) + a1 * bfbits2f(V1[j]) +       \
                a2 * bfbits2f(V2[j]) + a3 * bfbits2f(V3[j]);        \
  }

  for (int base = 0; base < deg; base += 64) {
    int cnt = deg - base;
    if (cnt > 64) cnt = 64;
    int mysrc = (lane < cnt) ? colv[start + base + lane] : 0;
    int nfull = cnt & ~3;
    if (nfull) {
      short8 v0, v1, v2, v3;
      float q0, q1, q2, q3;
      AG_LOAD(0, v0, v1, v2, v3, q0, q1, q2, q3);
      for (int e = 4; e < nfull; e += 4) {
        short8 w0 = v0, w1 = v1, w2 = v2, w3 = v3;
        float p0 = q0, p1 = q1, p2 = q2, p3 = q3;
        AG_LOAD(e, v0, v1, v2, v3, q0, q1, q2, q3);
        AG_ACC(w0, w1, w2, w3, p0, p1, p2, p3);
      }
      AG_ACC(v0, v1, v2, v3, q0, q1, q2, q3);
    }
    for (int e = nfull; e < cnt; e++) {
      int s0 = __shfl(mysrc, e);
      short8 v = *(const short8*)(hpc + (long)s0 * 512);
      float a = exleaky(svb[(long)s0 * 8 + h] + tvh);
      den += a;
#pragma unroll
      for (int j = 0; j < 8; j++) acc[j] += a * bfbits2f(v[j]);
    }
  }

  const float dinv = 1.f / den;
  if (mode == 0) {
    short8 o8;
#pragma unroll
    for (int j = 0; j < 8; j++) {
      float s = acc[j] * dinv;
      float ev = s > 0.f ? s : expm1f(s);
      o8[j] = f2bfbits(ev);
    }
    *(short8*)((bf16*)outp + (long)n * 512 + lane * 8) = o8;
  } else {
    float r[8];
#pragma unroll
    for (int j = 0; j < 8; j++) r[j] = acc[j] * dinv;
#pragma unroll
    for (int m = 8; m <= 32; m <<= 1)
#pragma unroll
      for (int j = 0; j < 8; j++) r[j] += __shfl_xor(r[j], m);
    if (lane < 8) {
      float* o = (float*)outp + (long)n * 128 + lane * 8;
#pragma unroll
      for (int j = 0; j < 8; j++) o[j] = r[j] * 0.125f;
    }
  }
}

// favec[o] = (hemb1[0,:] @ W1) @ aw1[:,o]  — one 256-thread block.
__global__ __launch_bounds__(256) void favec2_kernel(const void* __restrict__ hemb1,
                                                     const void* __restrict__ W1,
                                                     const void* __restrict__ aw1,
                                                     float* __restrict__ favec,
                                                     const int* __restrict__ flag) {
  const int f32 = flag[0];
  __shared__ float s_h[128];
  __shared__ float s_r[256];
  __shared__ float part[4][64];
  const int tid = threadIdx.x;
  if (tid < 128) s_h[tid] = ldin(hemb1, tid, f32);
  __syncthreads();
  float r = 0.f;
  for (int i = 0; i < 128; i++) r += s_h[i] * ldin(W1, (long)i * 256 + tid, f32);
  s_r[tid] = r;
  __syncthreads();
  const int o = tid & 63;
  const int wv = tid >> 6;
  float acc = 0.f;
#pragma unroll
  for (int kk = 0; kk < 64; kk++) {
    int k = wv * 64 + kk;
    acc += s_r[k] * ldin(aw1, (long)k * 64 + o, f32);
  }
  part[wv][o] = acc;
  __syncthreads();
  if (tid < 64) favec[o] = part[0][o] + part[1][o] + part[2][o] + part[3][o];
}

// ---------------------------------------------------------------------------
// Semantic attention + FC + log_softmax. 16 nodes per 256-thread block.
// ---------------------------------------------------------------------------
#define FN 16
__global__ __launch_bounds__(256) void final_kernel(const float* __restrict__ ta,
                                                    const float* __restrict__ favec,
                                                    const void* __restrict__ aw2,
                                                    const void* __restrict__ am,
                                                    const void* __restrict__ fcw,
                                                    const void* __restrict__ fcb,
                                                    void* __restrict__ out, int N,
                                                    const int* __restrict__ flag) {
  const int f32 = flag[0];
  __shared__ float s_w[64 * 64];
  __shared__ float s_fc[384];
  __shared__ float s_misc[130];
  __shared__ float s_ta[FN * 128];
  const int tid = threadIdx.x;
  const int n0 = blockIdx.x * FN;
  for (int i = tid; i < 4096; i += 256) s_w[i] = ldin(aw2, i, f32);
  for (int i = tid; i < 384; i += 256) s_fc[i] = ldin(fcw, i, f32);
  if (tid < 64) s_misc[tid] = favec[tid];
  else if (tid < 128) s_misc[tid] = ldin(am, tid - 64, f32);
  else if (tid < 130) s_misc[tid] = ldin(fcb, tid - 128, f32);
  for (int idx = tid; idx < FN * 128; idx += 256) {
    int ni = idx >> 7;
    int j = idx & 127;
    int k = j >> 1, r = j & 1;
    int n = n0 + ni;
    s_ta[idx] = (n < N) ? ta[(long)n * 128 + r * 64 + k] : 0.f;
  }
  __syncthreads();
  const int o = tid & 63;
  const int wv = tid >> 6;
#pragma unroll
  for (int ni4 = 0; ni4 < 4; ni4++) {
    const int ni = wv * 4 + ni4;
    const int n = n0 + ni;
    if (n >= N) continue;
    const float* tb = &s_ta[ni * 128];
    float acc0 = s_misc[o], acc1 = acc0;
#pragma unroll 8
    for (int k = 0; k < 64; k++) {
      float2 t2 = *(const float2*)(tb + k * 2);
      float w = s_w[k * 64 + o];
      acc0 += t2.x * w;
      acc1 += t2.y * w;
    }
    float ta0 = tb[o * 2];
    float ta1 = tb[o * 2 + 1];
    float amv = s_misc[64 + o];
    float p0 = tanhf(acc0) * amv;
    float p1 = tanhf(acc1) * amv;
#pragma unroll
    for (int off = 32; off > 0; off >>= 1) {
      p0 += __shfl_xor(p0, off);
      p1 += __shfl_xor(p1, off);
    }
    float mx = fmaxf(p0, p1);
    float e0 = __expf(p0 - mx), e1 = __expf(p1 - mx);
    float b0 = e0 / (e0 + e1), b1 = e1 / (e0 + e1);
    float fus = b0 * ta0 + b1 * ta1;
    float l0 = ta0 * s_fc[o * 2 + 0] + ta1 * s_fc[(64 + o) * 2 + 0] + fus * s_fc[(128 + o) * 2 + 0];
    float l1 = ta0 * s_fc[o * 2 + 1] + ta1 * s_fc[(64 + o) * 2 + 1] + fus * s_fc[(128 + o) * 2 + 1];
#pragma unroll
    for (int off = 32; off > 0; off >>= 1) {
      l0 += __shfl_xor(l0, off);
      l1 += __shfl_xor(l1, off);
    }
    if (o == 0) {
      l0 += s_misc[128];
      l1 += s_misc[129];
      float m2 = fmaxf(l0, l1);
      float lse = m2 + logf(__expf(l0 - m2) + __expf(l1 - m2));
      if (f32) {
        ((float*)out)[n * 2 + 0] = l0 - lse;
        ((float*)out)[n * 2 + 1] = l1 - lse;
      } else {
        ((bf16*)out)[n * 2 + 0] = __float2bfloat16(l0 - lse);
        ((bf16*)out)[n * 2 + 1] = __float2bfloat16(l1 - lse);
      }
    }
  }
}

extern "C" void kernel_launch(void* const* d_in, const int* in_sizes, int n_in,
                              void* d_out, int out_size, void* d_ws, size_t ws_size,
                              hipStream_t stream) {
  constexpr int N = 20000, E = 320000, H = 8, F0 = 128, FU = 256, FO = 64;
  const void* hemb[2] = {d_in[0], d_in[1]};
  const void* W[2] = {d_in[2], d_in[3]};
  const void* gw[2][2] = {{d_in[4], d_in[7]}, {d_in[10], d_in[13]}};
  const void* gasrc[2][2] = {{d_in[5], d_in[8]}, {d_in[11], d_in[14]}};
  const void* gatrg[2][2] = {{d_in[6], d_in[9]}, {d_in[12], d_in[15]}};
  const void* aw1 = d_in[16];
  const void* aw2 = d_in[17];
  const void* am = d_in[18];
  const void* fcw = d_in[19];
  const void* fcb = d_in[20];
  const int* edge[2] = {(const int*)d_in[21], (const int*)d_in[22]};

  const size_t szWg = (size_t)F0 * 512 * 2;
  const size_t szHp = (size_t)N * 512 * 2;
  const size_t szSv = (size_t)N * 8 * 4;
  size_t need = 0;
  auto addsz = [&](size_t b) { need += (b + 255) & ~(size_t)255; };
  addsz(4);
  addsz(szWg * 2);
  addsz(szHp * 2); addsz(szHp * 2);
  addsz(szSv * 2); addsz(szSv * 2);
  addsz((size_t)N * 128 * 4); addsz(256);
  addsz((size_t)2 * N * 4); addsz((size_t)2 * (N + 1) * 4);
  addsz((size_t)2 * N * 4); addsz((size_t)2 * E * 4);
  const bool batched = (ws_size >= need + 4096);
  const int TB = batched ? 2 : 1;

  char* p = (char*)d_ws;
  auto alloc = [&](size_t bytes) -> void* {
    void* r = (void*)p;
    p += (bytes + 255) & ~(size_t)255;
    return r;
  };
  int* flag = (int*)alloc(4);
  bf16* wg = (bf16*)alloc(szWg * 2);
  bf16* hp = (bf16*)alloc(szHp * TB);
  bf16* xbuf = (bf16*)alloc(szHp * TB);
  float* sv = (float*)alloc(szSv * TB);
  float* tv = (float*)alloc(szSv * TB);
  float* ta = (float*)alloc((size_t)N * 128 * 4);
  float* favec = (float*)alloc(256);
  int* degb = (int*)alloc((size_t)2 * N * 4);
  int* rpb = (int*)alloc((size_t)2 * (N + 1) * 4);
  int* filb = (int*)alloc((size_t)2 * N * 4);
  int* colb = (int*)alloc((size_t)2 * E * 4);

  detect_kernel<<<1, 64, 0, stream>>>(hemb[0], flag);

  // CSR build for both graphs in one pass
  hipMemsetAsync(degb, 0, (size_t)2 * N * 4, stream);
  hist2_kernel<<<(2 * E + 255) / 256, 256, 0, stream>>>(edge[0] + E, edge[1] + E, degb, E, N);
  scan_kernel<<<2, 1024, 0, stream>>>(degb, rpb, filb, N);
  fill2_kernel<<<(2 * E + 255) / 256, 256, 0, stream>>>(edge[0], edge[0] + E,
                                                        edge[1], edge[1] + E, filb, colb, E, N);

  // favec from inputs directly
  favec2_kernel<<<1, 256, 0, stream>>>(hemb[1], W[1], aw1, favec, flag);

  // Wg[t] = W[t] @ gw[t][0] : [128][512] bf16 ws (both types in one launch).
  // 1D grid: nx=1, ny=8 -> gridDim.x = 8 (tail decode handles it).
  {
    GArg gW{};
    for (int i = 0; i < 2; i++) {
      gW.A[i] = W[i]; gW.B[i] = gw[i][0]; gW.C[i] = wg + (size_t)i * F0 * 512;
      gW.sa[i] = nullptr; gW.sb[i] = nullptr; gW.sv[i] = nullptr; gW.tv[i] = nullptr;
    }
    gemm_mfma<<<dim3(8, 1, 2), 256, 0, stream>>>(gW, 1, 1, F0, FU, H * FO, flag);
  }

  const int gmx = (N + GBM - 1) / GBM;    // 157
  const int gfk = (N + FKBM - 1) / FKBM;  // 313
  const int npass = batched ? 1 : 2;
  const int TC = batched ? 2 : 1;

  auto hpP = [&](int b) { return hp + (size_t)b * N * 512; };
  auto xbufP = [&](int b) { return xbuf + (size_t)b * N * 512; };
  auto svP = [&](int b) { return sv + (size_t)b * N * 8; };
  auto tvP = [&](int b) { return tv + (size_t)b * N * 8; };

  for (int pass = 0; pass < npass; pass++) {
    int types[2] = {batched ? 0 : pass, batched ? 1 : pass};
    int bufs[2] = {0, batched ? 1 : 0};

    // hp layer 0: A = hemb (input, K=128), B = Wg (ws bf16) — full-K kernel
    GArg g1{};
    for (int i = 0; i < TC; i++) {
      int t = types[i], b = bufs[i];
      g1.A[i] = hemb[t]; g1.B[i] = wg + (size_t)t * F0 * 512; g1.C[i] = hpP(b);
      g1.sa[i] = gasrc[t][0]; g1.sb[i] = gatrg[t][0]; g1.sv[i] = svP(b); g1.tv[i] = tvP(b);
    }
    gemm_fullk<<<dim3(gfk, 1, TC), 256, 0, stream>>>(g1, N, flag);

    AArg a0{};
    for (int i = 0; i < TC; i++) {
      int t = types[i], b = bufs[i];
      a0.hp[i] = hpP(b); a0.sv[i] = svP(b); a0.tv[i] = tvP(b);
      a0.rp[i] = rpb + (size_t)t * (N + 1); a0.col[i] = colb + (size_t)t * E;
      a0.out[i] = xbufP(b);
    }
    aggregate<<<dim3((N + 3) / 4, TC), 256, 0, stream>>>(a0, N, 0);

    // hp layer 1: 1D grid gmx*8 with XCD-coresidency decode
    GArg g2{};
    for (int i = 0; i < TC; i++) {
      int t = types[i], b = bufs[i];
      g2.A[i] = xbufP(b); g2.B[i] = gw[t][1]; g2.C[i] = hpP(b);
      g2.sa[i] = gasrc[t][1]; g2.sb[i] = gatrg[t][1]; g2.sv[i] = svP(b); g2.tv[i] = tvP(b);
    }
    gemm_mfma<<<dim3(gmx * 8, 1, TC), 256, 0, stream>>>(g2, 0, 1, N, H * FO, H * FO, flag);

    AArg a1{};
    for (int i = 0; i < TC; i++) {
      int t = types[i], b = bufs[i];
      a1.hp[i] = hpP(b); a1.sv[i] = svP(b); a1.tv[i] = tvP(b);
      a1.rp[i] = rpb + (size_t)t * (N + 1); a1.col[i] = colb + (size_t)t * E;
      a1.out[i] = ta + (size_t)t * FO;
    }
    aggregate<<<dim3((N + 3) / 4, TC), 256, 0, stream>>>(a1, N, 1);
  }

  final_kernel<<<(N + FN - 1) / FN, 256, 0, stream>>>(ta, favec, aw2, am, fcw, fcb, d_out, N, flag);
}

// Round 14
// 529.360 us; speedup vs baseline: 1.1129x; 1.0541x over previous
//
#include <hip/hip_runtime.h>
#include <hip/hip_bf16.h>

// ---------------------------------------------------------------------------
// HetergatWOConcatFeat — round 15:
//  - B pre-transposed in WS (tr_kernel, one-time ~1.3MB): gemm staging for B
//    becomes A-style (contiguous 16B global reads + contiguous swizzled LDS
//    writes). Kills the 8x strided-gather per slot that every GEMM variant
//    carried (r13's LDS-scatter fix added 1.8e7 bank conflicts; this has 0).
//    gemm_mfma bmode=3 = pre-transposed ws B (used by g2, B=bt1);
//    gemm_fullk stages panels from wgT.
//  - XCD-coresidency 1D decode (r14, verified 575->558) kept.
//  - aggregate at its established floor (2x89us, 290MB, rounds 5-14) — kept.
// ---------------------------------------------------------------------------

typedef __hip_bfloat16 bf16;
typedef __attribute__((ext_vector_type(8))) short short8;
typedef __attribute__((ext_vector_type(4))) float f32x4;

__device__ __forceinline__ float bf2f(bf16 v) { return __bfloat162float(v); }
__device__ __forceinline__ float ldin(const void* p, long i, int f32) {
  return f32 ? ((const float*)p)[i] : bf2f(((const bf16*)p)[i]);
}
__device__ __forceinline__ short f2bfbits(float f) {
  bf16 h = __float2bfloat16(f);
  return *reinterpret_cast<short*>(&h);
}
__device__ __forceinline__ float bfbits2f(short b) {
  unsigned u = ((unsigned)(unsigned short)b) << 16;
  return __uint_as_float(u);
}

struct GArg {
  const void* A[2];
  const void* B[2];
  bf16* C[2];
  const void* sa[2];
  const void* sb[2];
  float* sv[2];
  float* tv[2];
};

struct AArg {
  const bf16* hp[2];
  const float* sv[2];
  const float* tv[2];
  const int* rp[2];
  const int* col[2];
  void* out[2];
};

// Detect input dtype: read first 2048 elements of hemb0 as bf16. If the data
// is really f32, the mantissa halves decode to huge/NaN values.
__global__ __launch_bounds__(64) void detect_kernel(const void* __restrict__ x,
                                                    int* __restrict__ flag) {
  int tid = threadIdx.x;
  float m = 0.f;
  for (int i = tid; i < 2048; i += 64) {
    float v = fabsf(bf2f(((const bf16*)x)[i]));
    if (!(v <= 1e3f)) v = 1e9f;  // NaN/Inf/big -> force detect
    m = fmaxf(m, v);
  }
#pragma unroll
  for (int off = 32; off; off >>= 1) m = fmaxf(m, __shfl_xor(m, off));
  if (tid == 0) flag[0] = (m > 1e3f) ? 1 : 0;
}

// ---------------------------------------------------------------------------
// tr_kernel: one-time weight transposes into WS (coalesced writes).
//  wgT[t][c*128 + k] = wg[t][k*512 + c]            (c<512, k<128)  — 256KB
//  bt1[t][c*512 + k] = gw1_t[((c>>6)*512 + k)*64 + (c&63)]          — 1MB
// ---------------------------------------------------------------------------
__global__ __launch_bounds__(256) void tr_kernel(const bf16* __restrict__ wg,
                                                 bf16* __restrict__ wgT,
                                                 const void* __restrict__ gw1a,
                                                 const void* __restrict__ gw1b,
                                                 bf16* __restrict__ bt1,
                                                 const int* __restrict__ flag) {
  const int f32 = flag[0];
  long i = (long)blockIdx.x * 256 + threadIdx.x;
  const long nW = 2L * 512 * 128;    // 131072
  const long nB = 2L * 512 * 512;    // 524288
  if (i < nW) {
    int t = (int)(i >> 16);          // 512*128 = 65536
    long r = i & 65535;
    int c = (int)(r >> 7), k = (int)(r & 127);
    wgT[i] = wg[(long)t * 65536 + (long)k * 512 + c];
  } else if (i < nW + nB) {
    long r = i - nW;
    int t = (int)(r >> 18);          // 512*512 = 262144
    long q = r & 262143;
    int c = (int)(q >> 9), k = (int)(q & 511);
    const void* g = t ? gw1b : gw1a;
    float v = ldin(g, ((long)(c >> 6) * 512 + k) * 64 + (c & 63), f32);
    bt1[r] = __float2bfloat16(v);
  }
}

// ---------------------------------------------------------------------------
// MFMA GEMM (K-step form): C[M][Nc] bf16 = A[M][K] @ B[K][Nc], fp32 accum.
// amode: 0 = A ws bf16; 1 = A input (dtype by flag).
// bmode: 0 = B row-major input; 1 = B head-blocked [H][K][64] input;
//        2 = B row-major WS bf16; 3 = B PRE-TRANSPOSED WS bf16 [Nc][K]
//        (A-style coalesced staging — preferred path).
// Tile BM=128, BN=64, BK=64; 256 threads / 4 waves; acc[2][4]. LDS 24KB.
// GRID IS 1D: gridDim.x = nx*8. Decode puts all 8 sharers of an A-panel at
// equal d%8 (same XCD under round-robin dispatch) -> panel fetched once/XCD.
// Fused st when sv[z] != null (Nc=512, head = y).
// ---------------------------------------------------------------------------
#define GBM 128
#define GBN 64
#define GBK 64

__device__ __forceinline__ int swz(int row, int kbyte) {
  return row * 128 + (kbyte ^ ((row & 7) << 4));
}

__global__ __launch_bounds__(256) void gemm_mfma(GArg g, int amode, int bmode,
                                                 int M, int K, int Nc,
                                                 const int* __restrict__ flag) {
  __shared__ bf16 As[GBM * GBK];
  __shared__ bf16 Bs[GBN * GBK];
  const int z = blockIdx.z;
  const void* __restrict__ A = g.A[z];
  const void* __restrict__ B = g.B[z];
  bf16* __restrict__ C = g.C[z];
  const void* stasrc = g.sa[z];
  const void* statrg = g.sb[z];
  float* svp = g.sv[z];
  float* tvp = g.tv[z];
  const int f32 = flag[0];
  const int af32 = (amode == 1) ? f32 : 0;
  const int bf32 = (bmode == 2 || bmode == 3) ? 0 : f32;

  // ---- XCD-coresidency decode: sharers of one A-panel share d%8 ----
  const int nx = gridDim.x >> 3;
  const int d = blockIdx.x;
  const int fullC = (gridDim.x >> 6) << 6;
  int x, y;
  if (d < fullC) {
    x = (d & 7) + ((d >> 6) << 3);
    y = (d >> 3) & 7;
  } else {
    int l = d - fullC;
    int xbase = fullC >> 3;
    int nrem = nx - xbase;
    x = xbase + l % nrem;
    y = l / nrem;
  }
  const int m0 = x * GBM;
  const int n0 = y * GBN;
  const int tid = threadIdx.x;
  const int lane = tid & 63;
  const int wrow = (tid >> 6) * 32;

  f32x4 acc[2][4];
#pragma unroll
  for (int m = 0; m < 2; m++)
#pragma unroll
    for (int n = 0; n < 4; n++)
#pragma unroll
      for (int r = 0; r < 4; r++) acc[m][n][r] = 0.f;

  for (int kt = 0; kt < K; kt += GBK) {
    // ---- stage A: 128 rows x 64 k, 1024 16B slots, 4/thread ----
#pragma unroll
    for (int j = 0; j < 4; j++) {
      int idx = tid + j * 256;       // 0..1023
      int row = idx >> 3;            // 0..127
      int ks = idx & 7;              // 16B slot within row
      int gm = m0 + row;
      short8 v;
#pragma unroll
      for (int e = 0; e < 8; e++) v[e] = 0;
      if (gm < M) {
        long base = (long)gm * K + kt + ks * 8;
        if (!af32) {
          v = *(const short8*)((const bf16*)A + base);
        } else {
          const float* Af = (const float*)A + base;
          float4 x0 = *(const float4*)Af;
          float4 x1 = *(const float4*)(Af + 4);
          v[0] = f2bfbits(x0.x); v[1] = f2bfbits(x0.y);
          v[2] = f2bfbits(x0.z); v[3] = f2bfbits(x0.w);
          v[4] = f2bfbits(x1.x); v[5] = f2bfbits(x1.y);
          v[6] = f2bfbits(x1.z); v[7] = f2bfbits(x1.w);
        }
      }
      *(short8*)((char*)As + swz(row, ks * 16)) = v;
    }
    // ---- stage B ----
    if (bmode == 3) {
      // pre-transposed [Nc][K]: A-style coalesced staging, 512 slots, 2/thread
      const bf16* BT = (const bf16*)B;
#pragma unroll
      for (int j = 0; j < 2; j++) {
        int idx = tid + j * 256;   // 0..511
        int c = idx >> 3;          // 0..63
        int ks = idx & 7;
        short8 v = *(const short8*)(BT + (long)(n0 + c) * K + kt + ks * 8);
        *(short8*)((char*)Bs + swz(c, ks * 16)) = v;
      }
    } else {
      // scalar-gather transpose (bmode 0/1/2)
      int n = tid & 63;
      int ks0 = tid >> 6;  // 0..3
#pragma unroll
      for (int jj = 0; jj < 2; jj++) {
        int ks = ks0 + jj * 4;     // 0..7
        int k = kt + ks * 8;
        int col = n0 + n;
        long base;
        int cstr;
        if (bmode == 1) { base = ((long)(col >> 6) * K + k) * 64 + (col & 63); cstr = 64; }
        else { base = (long)k * Nc + col; cstr = Nc; }
        short8 v;
        if (bf32) {
          const float* Bf = (const float*)B;
#pragma unroll
          for (int e = 0; e < 8; e++) v[e] = f2bfbits(Bf[base + (long)e * cstr]);
        } else {
          const bf16* Bh = (const bf16*)B;
#pragma unroll
          for (int e = 0; e < 8; e++) v[e] = *(const short*)&Bh[base + (long)e * cstr];
        }
        *(short8*)((char*)Bs + swz(n, ks * 16)) = v;
      }
    }
    __syncthreads();
    // ---- compute: 2 k-halves of 32, per wave 2x4 fragments ----
#pragma unroll
    for (int kh = 0; kh < 2; kh++) {
      int klane = kh * 64 + ((lane >> 4) << 4);
      short8 af[2], bfr[4];
#pragma unroll
      for (int m = 0; m < 2; m++) {
        int row = wrow + m * 16 + (lane & 15);
        af[m] = *(const short8*)((const char*)As + swz(row, klane));
      }
#pragma unroll
      for (int n = 0; n < 4; n++) {
        int col = n * 16 + (lane & 15);
        bfr[n] = *(const short8*)((const char*)Bs + swz(col, klane));
      }
#pragma unroll
      for (int m = 0; m < 2; m++)
#pragma unroll
        for (int n = 0; n < 4; n++)
          acc[m][n] = __builtin_amdgcn_mfma_f32_16x16x32_bf16(af[m], bfr[n], acc[m][n], 0, 0, 0);
    }
    __syncthreads();
  }
  // ---- fused st: s/t from fp32 acc (head h = y) ----
  if (svp) {
    const int h = y;
    const int cl = lane & 15;
    float av[4], bv[4];
#pragma unroll
    for (int n = 0; n < 4; n++) {
      av[n] = ldin(stasrc, h * 64 + n * 16 + cl, f32);
      bv[n] = ldin(statrg, h * 64 + n * 16 + cl, f32);
    }
#pragma unroll
    for (int m = 0; m < 2; m++) {
#pragma unroll
      for (int r = 0; r < 4; r++) {
        float s = 0.f, t = 0.f;
#pragma unroll
        for (int n = 0; n < 4; n++) {
          s += acc[m][n][r] * av[n];
          t += acc[m][n][r] * bv[n];
        }
#pragma unroll
        for (int off = 1; off <= 8; off <<= 1) {
          s += __shfl_xor(s, off);
          t += __shfl_xor(t, off);
        }
        int row = m0 + wrow + m * 16 + ((lane >> 4) << 2) + r;
        if (cl == 0 && row < M) {
          svp[(long)row * 8 + h] = s;
          tvp[(long)row * 8 + h] = t;
        }
      }
    }
  }
  // ---- C write ----
#pragma unroll
  for (int m = 0; m < 2; m++) {
#pragma unroll
    for (int r = 0; r < 4; r++) {
      int row = m0 + wrow + m * 16 + ((lane >> 4) << 2) + r;
      if (row < M) {
#pragma unroll
        for (int n = 0; n < 4; n++) {
          int col = n0 + n * 16 + (lane & 15);
          C[(long)row * Nc + col] = __float2bfloat16(acc[m][n][r]);
        }
      }
    }
  }
}

// ---------------------------------------------------------------------------
// gemm_fullk: specialized hp-layer-0 GEMM. K=128 (full in LDS), Nc=512.
// C = A[M][128] @ WgT^T, A input (dtype by flag), B = wgT [512][128] ws bf16
// (pre-transposed -> fully coalesced panel staging).
// BM=64, 256 threads / 4 waves. A staged ONCE (16KB); loop over 8 n-panels
// (head = p). LDS rows are 256B (K=128): swz256.
// ---------------------------------------------------------------------------
#define FKBM 64

__device__ __forceinline__ int swz256(int row, int kbyte) {
  return row * 256 + (kbyte ^ ((row & 7) << 4));
}

__global__ __launch_bounds__(256) void gemm_fullk(GArg g, int M,
                                                  const int* __restrict__ flag) {
  __shared__ bf16 As[FKBM * 128];   // 16KB
  __shared__ bf16 Bs[64 * 128];     // 16KB per panel
  const int z = blockIdx.z;
  const void* __restrict__ A = g.A[z];
  const bf16* __restrict__ BT = (const bf16*)g.B[z];   // wgT [512][128]
  bf16* __restrict__ C = g.C[z];
  const void* stasrc = g.sa[z];
  const void* statrg = g.sb[z];
  float* svp = g.sv[z];
  float* tvp = g.tv[z];
  const int f32 = flag[0];
  const int m0 = blockIdx.x * FKBM;
  const int tid = threadIdx.x;
  const int lane = tid & 63;
  const int wrow = (tid >> 6) * 16;

  // ---- stage A once: 64 rows x 128 k = 1024 16B slots, 4/thread ----
#pragma unroll
  for (int j = 0; j < 4; j++) {
    int idx = tid + j * 256;       // 0..1023
    int row = idx >> 4;            // 0..63
    int ks = idx & 15;             // 16 slots per 256B row
    int gm = m0 + row;
    short8 v;
#pragma unroll
    for (int e = 0; e < 8; e++) v[e] = 0;
    if (gm < M) {
      long base = (long)gm * 128 + ks * 8;
      if (!f32) {
        v = *(const short8*)((const bf16*)A + base);
      } else {
        const float* Af = (const float*)A + base;
        float4 x0 = *(const float4*)Af;
        float4 x1 = *(const float4*)(Af + 4);
        v[0] = f2bfbits(x0.x); v[1] = f2bfbits(x0.y);
        v[2] = f2bfbits(x0.z); v[3] = f2bfbits(x0.w);
        v[4] = f2bfbits(x1.x); v[5] = f2bfbits(x1.y);
        v[6] = f2bfbits(x1.z); v[7] = f2bfbits(x1.w);
      }
    }
    *(short8*)((char*)As + swz256(row, ks * 16)) = v;
  }

  for (int p = 0; p < 8; p++) {
    // ---- stage Bs for panel p from wgT (coalesced): rows p*64..+63 ----
#pragma unroll
    for (int j = 0; j < 4; j++) {
      int idx = tid + j * 256;     // 0..1023
      int c = idx >> 4;            // 0..63
      int ks = idx & 15;
      short8 v = *(const short8*)(BT + (long)(p * 64 + c) * 128 + ks * 8);
      *(short8*)((char*)Bs + swz256(c, ks * 16)) = v;
    }
    __syncthreads();
    // ---- compute panel: 4 k-blocks of 32, acc[4] ----
    f32x4 acc[4];
#pragma unroll
    for (int n = 0; n < 4; n++)
#pragma unroll
      for (int r = 0; r < 4; r++) acc[n][r] = 0.f;
#pragma unroll
    for (int kb = 0; kb < 4; kb++) {
      int klane = kb * 64 + ((lane >> 4) << 4);
      short8 af = *(const short8*)((const char*)As + swz256(wrow + (lane & 15), klane));
      short8 bfr[4];
#pragma unroll
      for (int n = 0; n < 4; n++)
        bfr[n] = *(const short8*)((const char*)Bs + swz256(n * 16 + (lane & 15), klane));
#pragma unroll
      for (int n = 0; n < 4; n++)
        acc[n] = __builtin_amdgcn_mfma_f32_16x16x32_bf16(af, bfr[n], acc[n], 0, 0, 0);
    }
    // ---- fused st for head p ----
    {
      const int cl = lane & 15;
      float av[4], bv[4];
#pragma unroll
      for (int n = 0; n < 4; n++) {
        av[n] = ldin(stasrc, p * 64 + n * 16 + cl, f32);
        bv[n] = ldin(statrg, p * 64 + n * 16 + cl, f32);
      }
#pragma unroll
      for (int r = 0; r < 4; r++) {
        float s = 0.f, t = 0.f;
#pragma unroll
        for (int n = 0; n < 4; n++) {
          s += acc[n][r] * av[n];
          t += acc[n][r] * bv[n];
        }
#pragma unroll
        for (int off = 1; off <= 8; off <<= 1) {
          s += __shfl_xor(s, off);
          t += __shfl_xor(t, off);
        }
        int row = m0 + wrow + ((lane >> 4) << 2) + r;
        if (cl == 0 && row < M) {
          svp[(long)row * 8 + p] = s;
          tvp[(long)row * 8 + p] = t;
        }
      }
    }
    // ---- C write for panel p ----
#pragma unroll
    for (int r = 0; r < 4; r++) {
      int row = m0 + wrow + ((lane >> 4) << 2) + r;
      if (row < M) {
#pragma unroll
        for (int n = 0; n < 4; n++) {
          int col = p * 64 + n * 16 + (lane & 15);
          C[(long)row * 512 + col] = __float2bfloat16(acc[n][r]);
        }
      }
    }
    __syncthreads();  // all waves done with Bs before next panel overwrites
  }
}

// ---- CSR build (both graphs in one pass; deg/fil [2N], rp [2(N+1)]) ----
__global__ void hist2_kernel(const int* __restrict__ trg0, const int* __restrict__ trg1,
                             int* __restrict__ deg, int E, int N) {
  int e = blockIdx.x * 256 + threadIdx.x;
  if (e < E) atomicAdd(&deg[trg0[e]], 1);
  else if (e < 2 * E) atomicAdd(&deg[N + trg1[e - E]], 1);
}

__global__ __launch_bounds__(1024) void scan_kernel(const int* __restrict__ degb,
                                                    int* __restrict__ rpb,
                                                    int* __restrict__ filb, int N) {
  const int* deg = degb + (long)blockIdx.x * N;
  int* row_ptr = rpb + (long)blockIdx.x * (N + 1);
  int* fil = filb + (long)blockIdx.x * N;
  __shared__ int sums[1024];
  int tid = threadIdx.x;
  int chunk = (N + 1023) >> 10;
  int start = tid * chunk;
  int end = start + chunk;
  if (start > N) start = N;
  if (end > N) end = N;
  int s = 0;
  for (int i = start; i < end; i++) s += deg[i];
  sums[tid] = s;
  __syncthreads();
  for (int off = 1; off < 1024; off <<= 1) {
    int add = (tid >= off) ? sums[tid - off] : 0;
    __syncthreads();
    sums[tid] += add;
    __syncthreads();
  }
  int run = (tid > 0) ? sums[tid - 1] : 0;
  for (int i = start; i < end; i++) {
    row_ptr[i] = run;
    fil[i] = run;
    run += deg[i];
  }
  if (tid == 0) row_ptr[N] = sums[1023];
}

__global__ void fill2_kernel(const int* __restrict__ src0, const int* __restrict__ trg0,
                             const int* __restrict__ src1, const int* __restrict__ trg1,
                             int* __restrict__ filb, int* __restrict__ colb, int E, int N) {
  int e = blockIdx.x * 256 + threadIdx.x;
  if (e < E) {
    int t = trg0[e];
    int pos = atomicAdd(&filb[t], 1);
    colb[pos] = src0[e];
  } else if (e < 2 * E) {
    int ee = e - E;
    int t = trg1[ee];
    int pos = atomicAdd(&filb[N + t], 1);
    colb[E + pos] = src1[ee];
  }
}

// ---------------------------------------------------------------------------
// GAT aggregation, fused single pass: out = (Σ_e ex_e · hp[src_e]) / (Σ_e ex_e).
// ONE wave per node (4 nodes per block). Lane c owns bytes [c*16,c*16+16) of
// the 1KB row (head h = c>>3). Edge srcs staged one-per-lane + __shfl
// broadcast; double-buffered 4-edge pipeline. blockIdx.y = type slot.
// ---------------------------------------------------------------------------
__device__ __forceinline__ float exleaky(float v) {
  v = v > 0.f ? v : 0.2f * v;
  return __expf(v);
}

__global__ __launch_bounds__(256) void aggregate(AArg aa, int N, int mode) {
  const int ty = blockIdx.y;
  const bf16* __restrict__ hpb = aa.hp[ty];
  const float* __restrict__ svb = aa.sv[ty];
  const float* __restrict__ tvb = aa.tv[ty];
  const int* __restrict__ rp = aa.rp[ty];
  const int* __restrict__ colv = aa.col[ty];
  void* __restrict__ outp = aa.out[ty];
  const int wid = threadIdx.x >> 6;
  const int lane = threadIdx.x & 63;
  const int n = blockIdx.x * 4 + wid;
  if (n >= N) return;
  const int start = rp[n];
  const int deg = rp[n + 1] - start;
  const int h = lane >> 3;
  const float tvh = tvb[(long)n * 8 + h];
  const bf16* __restrict__ hpc = hpb + lane * 8;

  float acc[8] = {0.f, 0.f, 0.f, 0.f, 0.f, 0.f, 0.f, 0.f};
  float den = 1e-16f;

#define AG_LOAD(EB, V0, V1, V2, V3, Q0, Q1, Q2, Q3)                 \
  {                                                                 \
    int t0 = __shfl(mysrc, (EB) + 0), t1 = __shfl(mysrc, (EB) + 1); \
    int t2 = __shfl(mysrc, (EB) + 2), t3 = __shfl(mysrc, (EB) + 3); \
    V0 = *(const short8*)(hpc + (long)t0 * 512);                    \
    V1 = *(const short8*)(hpc + (long)t1 * 512);                    \
    V2 = *(const short8*)(hpc + (long)t2 * 512);                    \
    V3 = *(const short8*)(hpc + (long)t3 * 512);                    \
    Q0 = svb[(long)t0 * 8 + h];                                     \
    Q1 = svb[(long)t1 * 8 + h];                                     \
    Q2 = svb[(long)t2 * 8 + h];                                     \
    Q3 = svb[(long)t3 * 8 + h];                                     \
  }
#define AG_ACC(V0, V1, V2, V3, Q0, Q1, Q2, Q3)                      \
  {                                                                 \
    float a0 = exleaky(Q0 + tvh), a1 = exleaky(Q1 + tvh);           \
    float a2 = exleaky(Q2 + tvh), a3 = exleaky(Q3 + tvh);           \
    den += a0 + a1 + a2 + a3;                                       \
    _Pragma("unroll")                                               \
    for (int j = 0; j < 8; j++)                                     \
      acc[j] += a0 * bfbits2f(V0[j]) + a1 * bfbits2f(V1[j]) +       \
                a2 * bfbits2f(V2[j]) + a3 * bfbits2f(V3[j]);        \
  }

  for (int base = 0; base < deg; base += 64) {
    int cnt = deg - base;
    if (cnt > 64) cnt = 64;
    int mysrc = (lane < cnt) ? colv[start + base + lane] : 0;
    int nfull = cnt & ~3;
    if (nfull) {
      short8 v0, v1, v2, v3;
      float q0, q1, q2, q3;
      AG_LOAD(0, v0, v1, v2, v3, q0, q1, q2, q3);
      for (int e = 4; e < nfull; e += 4) {
        short8 w0 = v0, w1 = v1, w2 = v2, w3 = v3;
        float p0 = q0, p1 = q1, p2 = q2, p3 = q3;
        AG_LOAD(e, v0, v1, v2, v3, q0, q1, q2, q3);
        AG_ACC(w0, w1, w2, w3, p0, p1, p2, p3);
      }
      AG_ACC(v0, v1, v2, v3, q0, q1, q2, q3);
    }
    for (int e = nfull; e < cnt; e++) {
      int s0 = __shfl(mysrc, e);
      short8 v = *(const short8*)(hpc + (long)s0 * 512);
      float a = exleaky(svb[(long)s0 * 8 + h] + tvh);
      den += a;
#pragma unroll
      for (int j = 0; j < 8; j++) acc[j] += a * bfbits2f(v[j]);
    }
  }

  const float dinv = 1.f / den;
  if (mode == 0) {
    short8 o8;
#pragma unroll
    for (int j = 0; j < 8; j++) {
      float s = acc[j] * dinv;
      float ev = s > 0.f ? s : expm1f(s);
      o8[j] = f2bfbits(ev);
    }
    *(short8*)((bf16*)outp + (long)n * 512 + lane * 8) = o8;
  } else {
    float r[8];
#pragma unroll
    for (int j = 0; j < 8; j++) r[j] = acc[j] * dinv;
#pragma unroll
    for (int m = 8; m <= 32; m <<= 1)
#pragma unroll
      for (int j = 0; j < 8; j++) r[j] += __shfl_xor(r[j], m);
    if (lane < 8) {
      float* o = (float*)outp + (long)n * 128 + lane * 8;
#pragma unroll
      for (int j = 0; j < 8; j++) o[j] = r[j] * 0.125f;
    }
  }
}

// favec[o] = (hemb1[0,:] @ W1) @ aw1[:,o]  — one 256-thread block.
__global__ __launch_bounds__(256) void favec2_kernel(const void* __restrict__ hemb1,
                                                     const void* __restrict__ W1,
                                                     const void* __restrict__ aw1,
                                                     float* __restrict__ favec,
                                                     const int* __restrict__ flag) {
  const int f32 = flag[0];
  __shared__ float s_h[128];
  __shared__ float s_r[256];
  __shared__ float part[4][64];
  const int tid = threadIdx.x;
  if (tid < 128) s_h[tid] = ldin(hemb1, tid, f32);
  __syncthreads();
  float r = 0.f;
  for (int i = 0; i < 128; i++) r += s_h[i] * ldin(W1, (long)i * 256 + tid, f32);
  s_r[tid] = r;
  __syncthreads();
  const int o = tid & 63;
  const int wv = tid >> 6;
  float acc = 0.f;
#pragma unroll
  for (int kk = 0; kk < 64; kk++) {
    int k = wv * 64 + kk;
    acc += s_r[k] * ldin(aw1, (long)k * 64 + o, f32);
  }
  part[wv][o] = acc;
  __syncthreads();
  if (tid < 64) favec[o] = part[0][o] + part[1][o] + part[2][o] + part[3][o];
}

// ---------------------------------------------------------------------------
// Semantic attention + FC + log_softmax. 16 nodes per 256-thread block.
// ---------------------------------------------------------------------------
#define FN 16
__global__ __launch_bounds__(256) void final_kernel(const float* __restrict__ ta,
                                                    const float* __restrict__ favec,
                                                    const void* __restrict__ aw2,
                                                    const void* __restrict__ am,
                                                    const void* __restrict__ fcw,
                                                    const void* __restrict__ fcb,
                                                    void* __restrict__ out, int N,
                                                    const int* __restrict__ flag) {
  const int f32 = flag[0];
  __shared__ float s_w[64 * 64];
  __shared__ float s_fc[384];
  __shared__ float s_misc[130];
  __shared__ float s_ta[FN * 128];
  const int tid = threadIdx.x;
  const int n0 = blockIdx.x * FN;
  for (int i = tid; i < 4096; i += 256) s_w[i] = ldin(aw2, i, f32);
  for (int i = tid; i < 384; i += 256) s_fc[i] = ldin(fcw, i, f32);
  if (tid < 64) s_misc[tid] = favec[tid];
  else if (tid < 128) s_misc[tid] = ldin(am, tid - 64, f32);
  else if (tid < 130) s_misc[tid] = ldin(fcb, tid - 128, f32);
  for (int idx = tid; idx < FN * 128; idx += 256) {
    int ni = idx >> 7;
    int j = idx & 127;
    int k = j >> 1, r = j & 1;
    int n = n0 + ni;
    s_ta[idx] = (n < N) ? ta[(long)n * 128 + r * 64 + k] : 0.f;
  }
  __syncthreads();
  const int o = tid & 63;
  const int wv = tid >> 6;
#pragma unroll
  for (int ni4 = 0; ni4 < 4; ni4++) {
    const int ni = wv * 4 + ni4;
    const int n = n0 + ni;
    if (n >= N) continue;
    const float* tb = &s_ta[ni * 128];
    float acc0 = s_misc[o], acc1 = acc0;
#pragma unroll 8
    for (int k = 0; k < 64; k++) {
      float2 t2 = *(const float2*)(tb + k * 2);
      float w = s_w[k * 64 + o];
      acc0 += t2.x * w;
      acc1 += t2.y * w;
    }
    float ta0 = tb[o * 2];
    float ta1 = tb[o * 2 + 1];
    float amv = s_misc[64 + o];
    float p0 = tanhf(acc0) * amv;
    float p1 = tanhf(acc1) * amv;
#pragma unroll
    for (int off = 32; off > 0; off >>= 1) {
      p0 += __shfl_xor(p0, off);
      p1 += __shfl_xor(p1, off);
    }
    float mx = fmaxf(p0, p1);
    float e0 = __expf(p0 - mx), e1 = __expf(p1 - mx);
    float b0 = e0 / (e0 + e1), b1 = e1 / (e0 + e1);
    float fus = b0 * ta0 + b1 * ta1;
    float l0 = ta0 * s_fc[o * 2 + 0] + ta1 * s_fc[(64 + o) * 2 + 0] + fus * s_fc[(128 + o) * 2 + 0];
    float l1 = ta0 * s_fc[o * 2 + 1] + ta1 * s_fc[(64 + o) * 2 + 1] + fus * s_fc[(128 + o) * 2 + 1];
#pragma unroll
    for (int off = 32; off > 0; off >>= 1) {
      l0 += __shfl_xor(l0, off);
      l1 += __shfl_xor(l1, off);
    }
    if (o == 0) {
      l0 += s_misc[128];
      l1 += s_misc[129];
      float m2 = fmaxf(l0, l1);
      float lse = m2 + logf(__expf(l0 - m2) + __expf(l1 - m2));
      if (f32) {
        ((float*)out)[n * 2 + 0] = l0 - lse;
        ((float*)out)[n * 2 + 1] = l1 - lse;
      } else {
        ((bf16*)out)[n * 2 + 0] = __float2bfloat16(l0 - lse);
        ((bf16*)out)[n * 2 + 1] = __float2bfloat16(l1 - lse);
      }
    }
  }
}

extern "C" void kernel_launch(void* const* d_in, const int* in_sizes, int n_in,
                              void* d_out, int out_size, void* d_ws, size_t ws_size,
                              hipStream_t stream) {
  constexpr int N = 20000, E = 320000, H = 8, F0 = 128, FU = 256, FO = 64;
  const void* hemb[2] = {d_in[0], d_in[1]};
  const void* W[2] = {d_in[2], d_in[3]};
  const void* gw[2][2] = {{d_in[4], d_in[7]}, {d_in[10], d_in[13]}};
  const void* gasrc[2][2] = {{d_in[5], d_in[8]}, {d_in[11], d_in[14]}};
  const void* gatrg[2][2] = {{d_in[6], d_in[9]}, {d_in[12], d_in[15]}};
  const void* aw1 = d_in[16];
  const void* aw2 = d_in[17];
  const void* am = d_in[18];
  const void* fcw = d_in[19];
  const void* fcb = d_in[20];
  const int* edge[2] = {(const int*)d_in[21], (const int*)d_in[22]};

  const size_t szWg = (size_t)F0 * 512 * 2;        // 128KB per type (bf16)
  const size_t szWgT = szWg;                       // transposed copy
  const size_t szBT1 = (size_t)512 * 512 * 2;      // 512KB per type
  const size_t szHp = (size_t)N * 512 * 2;
  const size_t szSv = (size_t)N * 8 * 4;
  size_t need = 0;
  auto addsz = [&](size_t b) { need += (b + 255) & ~(size_t)255; };
  addsz(4);
  addsz(szWg * 2); addsz(szWgT * 2); addsz(szBT1 * 2);
  addsz(szHp * 2); addsz(szHp * 2);
  addsz(szSv * 2); addsz(szSv * 2);
  addsz((size_t)N * 128 * 4); addsz(256);
  addsz((size_t)2 * N * 4); addsz((size_t)2 * (N + 1) * 4);
  addsz((size_t)2 * N * 4); addsz((size_t)2 * E * 4);
  const bool batched = (ws_size >= need + 4096);
  const int TB = batched ? 2 : 1;

  char* p = (char*)d_ws;
  auto alloc = [&](size_t bytes) -> void* {
    void* r = (void*)p;
    p += (bytes + 255) & ~(size_t)255;
    return r;
  };
  int* flag = (int*)alloc(4);
  bf16* wg = (bf16*)alloc(szWg * 2);
  bf16* wgT = (bf16*)alloc(szWgT * 2);
  bf16* bt1 = (bf16*)alloc(szBT1 * 2);
  bf16* hp = (bf16*)alloc(szHp * TB);
  bf16* xbuf = (bf16*)alloc(szHp * TB);
  float* sv = (float*)alloc(szSv * TB);
  float* tv = (float*)alloc(szSv * TB);
  float* ta = (float*)alloc((size_t)N * 128 * 4);
  float* favec = (float*)alloc(256);
  int* degb = (int*)alloc((size_t)2 * N * 4);
  int* rpb = (int*)alloc((size_t)2 * (N + 1) * 4);
  int* filb = (int*)alloc((size_t)2 * N * 4);
  int* colb = (int*)alloc((size_t)2 * E * 4);

  detect_kernel<<<1, 64, 0, stream>>>(hemb[0], flag);

  // CSR build for both graphs in one pass
  hipMemsetAsync(degb, 0, (size_t)2 * N * 4, stream);
  hist2_kernel<<<(2 * E + 255) / 256, 256, 0, stream>>>(edge[0] + E, edge[1] + E, degb, E, N);
  scan_kernel<<<2, 1024, 0, stream>>>(degb, rpb, filb, N);
  fill2_kernel<<<(2 * E + 255) / 256, 256, 0, stream>>>(edge[0], edge[0] + E,
                                                        edge[1], edge[1] + E, filb, colb, E, N);

  // favec from inputs directly
  favec2_kernel<<<1, 256, 0, stream>>>(hemb[1], W[1], aw1, favec, flag);

  // Wg[t] = W[t] @ gw[t][0] : [128][512] bf16 ws (both types in one launch).
  {
    GArg gW{};
    for (int i = 0; i < 2; i++) {
      gW.A[i] = W[i]; gW.B[i] = gw[i][0]; gW.C[i] = wg + (size_t)i * F0 * 512;
      gW.sa[i] = nullptr; gW.sb[i] = nullptr; gW.sv[i] = nullptr; gW.tv[i] = nullptr;
    }
    gemm_mfma<<<dim3(8, 1, 2), 256, 0, stream>>>(gW, 1, 1, F0, FU, H * FO, flag);
  }

  // One-time transposes: wg -> wgT, gw[t][1] -> bt1
  tr_kernel<<<2560, 256, 0, stream>>>(wg, wgT, gw[0][1], gw[1][1], bt1, flag);

  const int gmx = (N + GBM - 1) / GBM;    // 157
  const int gfk = (N + FKBM - 1) / FKBM;  // 313
  const int npass = batched ? 1 : 2;
  const int TC = batched ? 2 : 1;

  auto hpP = [&](int b) { return hp + (size_t)b * N * 512; };
  auto xbufP = [&](int b) { return xbuf + (size_t)b * N * 512; };
  auto svP = [&](int b) { return sv + (size_t)b * N * 8; };
  auto tvP = [&](int b) { return tv + (size_t)b * N * 8; };

  for (int pass = 0; pass < npass; pass++) {
    int types[2] = {batched ? 0 : pass, batched ? 1 : pass};
    int bufs[2] = {0, batched ? 1 : 0};

    // hp layer 0: A = hemb (input, K=128), B = wgT — full-K kernel
    GArg g1{};
    for (int i = 0; i < TC; i++) {
      int t = types[i], b = bufs[i];
      g1.A[i] = hemb[t]; g1.B[i] = wgT + (size_t)t * 512 * 128; g1.C[i] = hpP(b);
      g1.sa[i] = gasrc[t][0]; g1.sb[i] = gatrg[t][0]; g1.sv[i] = svP(b); g1.tv[i] = tvP(b);
    }
    gemm_fullk<<<dim3(gfk, 1, TC), 256, 0, stream>>>(g1, N, flag);

    AArg a0{};
    for (int i = 0; i < TC; i++) {
      int t = types[i], b = bufs[i];
      a0.hp[i] = hpP(b); a0.sv[i] = svP(b); a0.tv[i] = tvP(b);
      a0.rp[i] = rpb + (size_t)t * (N + 1); a0.col[i] = colb + (size_t)t * E;
      a0.out[i] = xbufP(b);
    }
    aggregate<<<dim3((N + 3) / 4, TC), 256, 0, stream>>>(a0, N, 0);

    // hp layer 1: 1D grid gmx*8, XCD decode, B = bt1 (pre-transposed)
    GArg g2{};
    for (int i = 0; i < TC; i++) {
      int t = types[i], b = bufs[i];
      g2.A[i] = xbufP(b); g2.B[i] = bt1 + (size_t)t * 512 * 512; g2.C[i] = hpP(b);
      g2.sa[i] = gasrc[t][1]; g2.sb[i] = gatrg[t][1]; g2.sv[i] = svP(b); g2.tv[i] = tvP(b);
    }
    gemm_mfma<<<dim3(gmx * 8, 1, TC), 256, 0, stream>>>(g2, 0, 3, N, H * FO, H * FO, flag);

    AArg a1{};
    for (int i = 0; i < TC; i++) {
      int t = types[i], b = bufs[i];
      a1.hp[i] = hpP(b); a1.sv[i] = svP(b); a1.tv[i] = tvP(b);
      a1.rp[i] = rpb + (size_t)t * (N + 1); a1.col[i] = colb + (size_t)t * E;
      a1.out[i] = ta + (size_t)t * FO;
    }
    aggregate<<<dim3((N + 3) / 4, TC), 256, 0, stream>>>(a1, N, 1);
  }

  final_kernel<<<(N + FN - 1) / FN, 256, 0, stream>>>(ta, favec, aw2, am, fcw, fcb, d_out, N, flag);
}